// Round 1
// baseline (2409.440 us; speedup 1.0000x reference)
//
#include <hip/hip_runtime.h>

#define B_   2
#define S_   1024
#define D_   1024
#define H_   8
#define V_   32000
#define SP1_ 1025

// ---------------------------------------------------------------------------
// ws layout (floats):
//   [0, 1024)                     E_sum  (column sums of wte; divide by V at use)
//   [1024, 1024 + B*H*S*D)        y      (b,h,s,d) contiguous, post-softmax,
//                                        already scaled by wn[s]*W_LR[h]/l
// ---------------------------------------------------------------------------

__global__ __launch_bounds__(256) void k_wte_sum(const float* __restrict__ wte,
                                                 float* __restrict__ wsE) {
    const int tid = threadIdx.x;
    const int v0  = blockIdx.x * 125;          // 256 blocks * 125 rows = 32000
    float s0 = 0.f, s1 = 0.f, s2 = 0.f, s3 = 0.f;
    for (int i = 0; i < 125; ++i) {
        const float* row = wte + (size_t)(v0 + i) * D_;
        s0 += row[tid];
        s1 += row[tid + 256];
        s2 += row[tid + 512];
        s3 += row[tid + 768];
    }
    atomicAdd(&wsE[tid],        s0);
    atomicAdd(&wsE[tid + 256],  s1);
    atomicAdd(&wsE[tid + 512],  s2);
    atomicAdd(&wsE[tid + 768],  s3);
}

// ---------------------------------------------------------------------------
// Flash-style causal attention, one (b,h,16-row q-tile) per block, fp32.
// scores = p[q+1] . (p[k] * Wq*Wk)  (Wqk folded into staged K tile)
// Online softmax: m/l per row, PV accumulated unnormalized in registers.
// Epilogue folds  wn[s] * W_LR[h] / l.
// ---------------------------------------------------------------------------
__global__ __launch_bounds__(256) void k_attn(const float* __restrict__ e,
                                              const float* __restrict__ p,
                                              const float* __restrict__ wq,
                                              const float* __restrict__ wk,
                                              const float* __restrict__ wv,
                                              const float* __restrict__ wlr,
                                              const float* __restrict__ wsE,
                                              float* __restrict__ ysc) {
    __shared__ __align__(16) float Kc[16][260];     // K-tile chunk, *Wqk folded (stride 260 -> 2-way bank = free)
    __shared__ __align__(16) float Stile[16][20];   // scores -> probs, [q][kk], stride 20 (80B, f4-aligned)
    __shared__ __align__(16) float Wqk[D_];         // Wq*Wk for this head
    __shared__ float m_s[16], l_s[16], sc_s[16];

    const int tid = threadIdx.x;
    const int bid = blockIdx.x;
    // work-descending dispatch: heaviest q-tiles first across all (b,h)
    const int bh  = bid & 15;                 // b*H + h
    const int qt  = 63 - (bid >> 4);          // q-tile index, 63..0
    const int b   = bh >> 3;
    const int h   = bh & 7;
    const int q0  = qt << 4;

    const int q   = tid >> 4;                 // phase-A row role (0..15)
    const int kk  = tid & 15;                 // phase-A col role (0..15)
    const int c0  = tid << 2;                 // phase-B column base (4 cols/thread)

    // Wqk into LDS (once per block)
    {
        float4 w1 = *(const float4*)&wq[h * D_ + tid * 4];
        float4 w2 = *(const float4*)&wk[h * D_ + tid * 4];
        float4 r; r.x = w1.x * w2.x; r.y = w1.y * w2.y; r.z = w1.z * w2.z; r.w = w1.w * w2.w;
        *(float4*)&Wqk[tid * 4] = r;
    }
    if (tid < 16) { m_s[tid] = -1e30f; l_s[tid] = 0.f; }
    __syncthreads();

    const float invV = 1.0f / (float)V_;
    float4 E4, Wv4;
    E4.x = wsE[c0 + 0] * invV; E4.y = wsE[c0 + 1] * invV;
    E4.z = wsE[c0 + 2] * invV; E4.w = wsE[c0 + 3] * invV;
    Wv4 = *(const float4*)&wv[h * D_ + c0];

    float acc[16][4];
#pragma unroll
    for (int i = 0; i < 16; ++i) { acc[i][0] = 0.f; acc[i][1] = 0.f; acc[i][2] = 0.f; acc[i][3] = 0.f; }

    const int    qg = q0 + q;
    const float* pq = p + ((size_t)b * SP1_ + (qg + 1)) * D_;   // Q row (p shifted by +1)

    for (int kt = 0; kt <= qt; ++kt) {
        const int k0 = kt << 4;
        float s = 0.f;

        // ---- phase A: scores, d in 4 chunks of 256 ----
        for (int dc = 0; dc < 4; ++dc) {
            {   // stage Kc[row][0..255] = p[b,k0+row,dc*256+col] * Wqk
                const int row = tid >> 4, l16 = tid & 15;
                const float* pk = p + ((size_t)b * SP1_ + (k0 + row)) * D_ + dc * 256;
#pragma unroll
                for (int jj = 0; jj < 4; ++jj) {
                    const int col = l16 * 4 + jj * 64;
                    float4 a = *(const float4*)&pk[col];
                    float4 w = *(const float4*)&Wqk[dc * 256 + col];
                    float4 r; r.x = a.x * w.x; r.y = a.y * w.y; r.z = a.z * w.z; r.w = a.w * w.w;
                    *(float4*)&Kc[row][col] = r;
                }
            }
            __syncthreads();
            const float* pqc = pq + dc * 256;
#pragma unroll 8
            for (int j = 0; j < 64; ++j) {
                float4 a  = *(const float4*)&pqc[j * 4];      // broadcast within 16-lane group
                float4 kc = *(const float4*)&Kc[kk][j * 4];
                s += a.x * kc.x + a.y * kc.y + a.z * kc.z + a.w * kc.w;
            }
            __syncthreads();
        }

        // causal mask within diagonal tile
        if (k0 + kk > qg) s = -1e30f;

        // ---- online softmax (16-lane groups share a q-row) ----
        float rmax = s;
#pragma unroll
        for (int off = 8; off; off >>= 1) rmax = fmaxf(rmax, __shfl_xor(rmax, off, 16));
        const float m_old = m_s[q];
        const float m_new = fmaxf(m_old, rmax);
        const float pval  = __expf(s - m_new);
        float rsum = pval;
#pragma unroll
        for (int off = 8; off; off >>= 1) rsum += __shfl_xor(rsum, off, 16);
        if (kk == 0) {
            const float scale = __expf(m_old - m_new);
            sc_s[q] = scale;
            l_s[q]  = l_s[q] * scale + rsum;
            m_s[q]  = m_new;
        }
        Stile[q][kk] = pval;
        __syncthreads();

        // ---- phase B: rescale + PV accumulate (thread owns cols c0..c0+3) ----
#pragma unroll
        for (int qq = 0; qq < 16; ++qq) {
            const float scq = sc_s[qq];
            acc[qq][0] *= scq; acc[qq][1] *= scq; acc[qq][2] *= scq; acc[qq][3] *= scq;
        }
#pragma unroll 1
        for (int kkc = 0; kkc < 4; ++kkc) {
            float4 Vr[4];
#pragma unroll
            for (int i = 0; i < 4; ++i) {
                const int k = k0 + kkc * 4 + i;
                float4 ev = *(const float4*)&e[((size_t)b * S_ + k) * D_ + c0];
                Vr[i].x = (ev.x - E4.x) * Wv4.x;
                Vr[i].y = (ev.y - E4.y) * Wv4.y;
                Vr[i].z = (ev.z - E4.z) * Wv4.z;
                Vr[i].w = (ev.w - E4.w) * Wv4.w;
            }
#pragma unroll
            for (int qq = 0; qq < 16; ++qq) {
                float4 pv = *(const float4*)&Stile[qq][kkc * 4];
                acc[qq][0] += pv.x * Vr[0].x + pv.y * Vr[1].x + pv.z * Vr[2].x + pv.w * Vr[3].x;
                acc[qq][1] += pv.x * Vr[0].y + pv.y * Vr[1].y + pv.z * Vr[2].y + pv.w * Vr[3].y;
                acc[qq][2] += pv.x * Vr[0].z + pv.y * Vr[1].z + pv.z * Vr[2].z + pv.w * Vr[3].z;
                acc[qq][3] += pv.x * Vr[0].w + pv.y * Vr[1].w + pv.z * Vr[2].w + pv.w * Vr[3].w;
            }
        }
        __syncthreads();   // protect Stile/sc_s before next tile overwrites
    }

    // ---- epilogue: fold wn * W_LR / l, store y (b,h,s,d) ----
    const float wlrh = wlr[h];
#pragma unroll
    for (int qq = 0; qq < 16; ++qq) {
        const int   qgq  = q0 + qq;
        const float coef = wlrh / ((float)(qgq + 1) * l_s[qq]);
        float4 r;
        r.x = acc[qq][0] * coef; r.y = acc[qq][1] * coef;
        r.z = acc[qq][2] * coef; r.w = acc[qq][3] * coef;
        *(float4*)&ysc[((size_t)bh * S_ + qgq) * D_ + c0] = r;
    }
}

// ---------------------------------------------------------------------------
// out[b] = reshape(y[b], 1024x8192) @ W_o  (+ b-term on kh==0), split-K=2,
// 128x128 tile, 8x8 per thread, atomicAdd into zeroed d_out.
// ---------------------------------------------------------------------------
__global__ __launch_bounds__(256) void k_out(const float* __restrict__ ysc,
                                             const float* __restrict__ wo,
                                             const float* __restrict__ e,
                                             const float* __restrict__ wsE,
                                             float* __restrict__ out) {
    __shared__ __align__(16) float Alds[16][132];   // [k][m] transposed
    __shared__ __align__(16) float Blds[16][132];   // [k][n]

    const int tid = threadIdx.x;
    const int n0  = blockIdx.x * 128;
    const int m0  = blockIdx.y * 128;
    const int kh  = blockIdx.z;                     // K half: 0 or 1
    const int tx  = tid & 15, ty = tid >> 4;

    float acc[8][8];
#pragma unroll
    for (int i = 0; i < 8; ++i)
#pragma unroll
        for (int j = 0; j < 8; ++j) acc[i][j] = 0.f;

    const int    b     = m0 >> 10;                  // tile never straddles batch
    const size_t Abase = (size_t)b * (H_ * (size_t)S_ * D_);
    const int    r0    = m0 & 1023;

    for (int kc = 0; kc < 256; ++kc) {
        const int k0 = kh * 4096 + kc * 16;
        {   // stage A (transpose to [k][m])
            const int row = tid >> 1;
            const int cc  = (tid & 1) * 8;
            const float* src = ysc + Abase + (size_t)(r0 + row) * 8192 + k0 + cc;
            float4 a0 = *(const float4*)&src[0];
            float4 a1 = *(const float4*)&src[4];
            Alds[cc + 0][row] = a0.x; Alds[cc + 1][row] = a0.y;
            Alds[cc + 2][row] = a0.z; Alds[cc + 3][row] = a0.w;
            Alds[cc + 4][row] = a1.x; Alds[cc + 5][row] = a1.y;
            Alds[cc + 6][row] = a1.z; Alds[cc + 7][row] = a1.w;
        }
        {   // stage B
            const int kr = tid >> 4;
            const int nn = (tid & 15) * 8;
            const float* src = wo + (size_t)(k0 + kr) * 1024 + n0 + nn;
            *(float4*)&Blds[kr][nn]     = *(const float4*)&src[0];
            *(float4*)&Blds[kr][nn + 4] = *(const float4*)&src[4];
        }
        __syncthreads();
#pragma unroll 4
        for (int k = 0; k < 16; ++k) {
            float4 a0 = *(const float4*)&Alds[k][ty * 4];
            float4 a1 = *(const float4*)&Alds[k][64 + ty * 4];
            float4 b0 = *(const float4*)&Blds[k][tx * 4];
            float4 b1 = *(const float4*)&Blds[k][64 + tx * 4];
            const float av[8] = {a0.x, a0.y, a0.z, a0.w, a1.x, a1.y, a1.z, a1.w};
            const float bv[8] = {b0.x, b0.y, b0.z, b0.w, b1.x, b1.y, b1.z, b1.w};
#pragma unroll
            for (int i = 0; i < 8; ++i)
#pragma unroll
                for (int j = 0; j < 8; ++j) acc[i][j] += av[i] * bv[j];
        }
        __syncthreads();
    }

    // epilogue: atomicAdd partials; kh==0 also adds the exact b-term
    const float invV = 1.0f / (float)V_;
#pragma unroll
    for (int i = 0; i < 8; ++i) {
        const int lr = ((i >> 2) * 64) + ty * 4 + (i & 3);
        const int m  = m0 + lr;
        const int r  = m & 1023;
        const float wn = 1.0f / (float)(r + 1);
#pragma unroll
        for (int jg = 0; jg < 2; ++jg) {
            const int nc = n0 + jg * 64 + tx * 4;
            float add[4] = {0.f, 0.f, 0.f, 0.f};
            if (kh == 0) {
                float4 e0v = *(const float4*)&e[(size_t)r * 1024 + nc];
                float4 e1v = *(const float4*)&e[(size_t)(1024 * 1024) + (size_t)r * 1024 + nc];
                float4 Ev  = *(const float4*)&wsE[nc];
                add[0] = (e0v.x + e1v.x - 2.f * Ev.x * invV) * wn;
                add[1] = (e0v.y + e1v.y - 2.f * Ev.y * invV) * wn;
                add[2] = (e0v.z + e1v.z - 2.f * Ev.z * invV) * wn;
                add[3] = (e0v.w + e1v.w - 2.f * Ev.w * invV) * wn;
            }
#pragma unroll
            for (int jj = 0; jj < 4; ++jj) {
                const int j = (jg << 2) + jj;
                atomicAdd(&out[(size_t)m * 1024 + nc + jj], acc[i][j] + add[jj]);
            }
        }
    }
}

// ---------------------------------------------------------------------------
extern "C" void kernel_launch(void* const* d_in, const int* in_sizes, int n_in,
                              void* d_out, int out_size, void* d_ws, size_t ws_size,
                              hipStream_t stream) {
    const float* e   = (const float*)d_in[0];
    const float* p   = (const float*)d_in[1];
    const float* wte = (const float*)d_in[2];
    const float* wq  = (const float*)d_in[3];
    const float* wk  = (const float*)d_in[4];
    const float* wv  = (const float*)d_in[5];
    const float* wlr = (const float*)d_in[6];
    const float* wo  = (const float*)d_in[7];
    float* out = (float*)d_out;

    float* wsE = (float*)d_ws;
    float* ysc = wsE + 1024;

    hipMemsetAsync(wsE, 0, 1024 * sizeof(float), stream);
    hipMemsetAsync(out, 0, (size_t)B_ * S_ * D_ * sizeof(float), stream);

    k_wte_sum<<<256, 256, 0, stream>>>(wte, wsE);
    k_attn<<<1024, 256, 0, stream>>>(e, p, wq, wk, wv, wlr, wsE, ysc);
    k_out<<<dim3(8, 16, 2), 256, 0, stream>>>(ysc, wo, e, wsE, out);
}

// Round 4
// 507.858 us; speedup vs baseline: 4.7443x; 4.7443x over previous
//
#include <hip/hip_runtime.h>

#define B_   2
#define S_   1024
#define D_   1024
#define H_   8
#define V_   32000
#define SP1_ 1025

typedef __attribute__((ext_vector_type(4))) float  f32x4;
typedef __attribute__((ext_vector_type(8))) __bf16 bf16x8;

__device__ inline ushort f2bf(float x) {            // RNE float -> bf16 bits
    union { float f; unsigned u; } v; v.f = x;
    unsigned r = v.u + 0x7FFFu + ((v.u >> 16) & 1u);
    return (ushort)(r >> 16);
}
__device__ inline float bf2f(ushort u) {
    union { unsigned u; float f; } v; v.u = (unsigned)u << 16; return v.f;
}

__device__ inline void gload_lds16(const void* g, void* l) {
    __builtin_amdgcn_global_load_lds((const __attribute__((address_space(1))) void*)g,
                                     (__attribute__((address_space(3))) void*)l,
                                     16, 0, 0);
}

// ---------------------------------------------------------------------------
// wte column sums (divide by V at use) — shared by both paths
// ---------------------------------------------------------------------------
__global__ __launch_bounds__(256) void k_wte_sum(const float* __restrict__ wte,
                                                 float* __restrict__ wsE) {
    const int tid = threadIdx.x;
    const int v0  = blockIdx.x * 125;
    float s0 = 0.f, s1 = 0.f, s2 = 0.f, s3 = 0.f;
    for (int i = 0; i < 125; ++i) {
        const float* row = wte + (size_t)(v0 + i) * D_;
        s0 += row[tid]; s1 += row[tid + 256]; s2 += row[tid + 512]; s3 += row[tid + 768];
    }
    atomicAdd(&wsE[tid], s0);       atomicAdd(&wsE[tid + 256], s1);
    atomicAdd(&wsE[tid + 512], s2); atomicAdd(&wsE[tid + 768], s3);
}

// ===========================================================================
// FAST PATH (needs 4 KB + 100 MB ws): bf16 MFMA pipeline
// ===========================================================================

// Shared NT-GEMM core: C(128x128) += A(128xK) * B(128xK)^T, bf16, BK=32.
// 4 waves; wave (w>>1, w&1) owns a 64x64 quadrant (4x4 frags of 16x16x32).
// Staging via global_load_lds width=16, linear LDS [128][32].
__device__ __forceinline__ void gemm_nt_core(const ushort* __restrict__ A,
                                             const ushort* __restrict__ B,
                                             int lda, int ldb, int kSteps,
                                             ushort* As, ushort* Bs,
                                             f32x4 acc[4][4]) {
    const int tid = threadIdx.x;
    const int w   = tid >> 6;
    const int l   = tid & 63;
    const int sr  = l >> 2;          // staging row-sub 0..15
    const int sc  = (l & 3) * 8;     // staging col-octet
    const int fr  = l & 15;          // frag row/col
    const int fko = (l >> 4) * 8;    // frag k-octet

    const ushort* a0 = A + (size_t)sr * lda + sc;
    const ushort* b0 = B + (size_t)sr * ldb + sc;

    for (int kt = 0; kt < kSteps; ++kt) {
        const int k0 = kt * 32;
#pragma unroll
        for (int i = 0; i < 2; ++i) {
            const int c = w * 2 + i;                       // chunk -> rows c*16..+15
            gload_lds16(a0 + (size_t)(c * 16) * lda + k0, As + c * 512);
            gload_lds16(b0 + (size_t)(c * 16) * ldb + k0, Bs + c * 512);
        }
        __syncthreads();
        bf16x8 av[4], bv[4];
#pragma unroll
        for (int m = 0; m < 4; ++m)
            av[m] = *(const bf16x8*)(As + ((w >> 1) * 64 + m * 16 + fr) * 32 + fko);
#pragma unroll
        for (int n = 0; n < 4; ++n)
            bv[n] = *(const bf16x8*)(Bs + ((w & 1) * 64 + n * 16 + fr) * 32 + fko);
#pragma unroll
        for (int m = 0; m < 4; ++m)
#pragma unroll
            for (int n = 0; n < 4; ++n)
                acc[m][n] = __builtin_amdgcn_mfma_f32_16x16x32_bf16(av[m], bv[n], acc[m][n], 0, 0, 0);
        __syncthreads();
    }
}

#define ACC_INIT(acc)                                            \
    f32x4 acc[4][4];                                             \
    _Pragma("unroll") for (int m_ = 0; m_ < 4; ++m_)             \
        _Pragma("unroll") for (int n_ = 0; n_ < 4; ++n_)         \
            acc[m_][n_] = (f32x4){0.f, 0.f, 0.f, 0.f};

// scores[bh][q][k] = Q[b] . K[bh]^T  -> bf16 into SCP (triangular tiles)
__global__ __launch_bounds__(256) void k_qk(const ushort* __restrict__ Q,
                                            const ushort* __restrict__ K,
                                            ushort* __restrict__ SCP) {
    __shared__ __align__(16) ushort As[128 * 32], Bs[128 * 32];
    const int qt = blockIdx.x, kt = blockIdx.y, bh = blockIdx.z;
    if (kt > qt) return;
    ACC_INIT(acc);
    const ushort* A  = Q + (size_t)(bh >> 3) * (S_ * D_) + (size_t)(qt * 128) * D_;
    const ushort* Bp = K + (size_t)bh * (S_ * D_) + (size_t)(kt * 128) * D_;
    gemm_nt_core(A, Bp, D_, D_, 32, As, Bs, acc);
    ushort* C = SCP + (size_t)bh * (S_ * S_) + (size_t)(qt * 128) * S_ + kt * 128;
    const int w = threadIdx.x >> 6, l = threadIdx.x & 63;
    const int r0 = (w >> 1) * 64 + (l >> 4) * 4;
    const int c0 = (w & 1) * 64 + (l & 15);
#pragma unroll
    for (int m = 0; m < 4; ++m)
#pragma unroll
        for (int n = 0; n < 4; ++n)
#pragma unroll
            for (int j = 0; j < 4; ++j)
                C[(size_t)(r0 + m * 16 + j) * S_ + c0 + n * 16] = f2bf(acc[m][n][j]);
}

// in-place row softmax over k<=q; folds wlr[h]*wn[q]/l; zeros tail to the
// 128-multiple so PV can run dense tiles.
__global__ __launch_bounds__(256) void k_softmax(ushort* __restrict__ SCP,
                                                 const float* __restrict__ wlr) {
    const int q = blockIdx.x, bh = blockIdx.y, h = bh & 7;
    const int tid = threadIdx.x;
    ushort* row = SCP + (size_t)bh * (S_ * S_) + (size_t)q * S_;
    const int len = q + 1;
    const int k0  = tid * 4;
    const ushort4 rv = *(const ushort4*)&row[k0];
    float v[4]; float mx = -1e30f;
    v[0] = (k0 + 0 < len) ? bf2f(rv.x) : -1e30f;
    v[1] = (k0 + 1 < len) ? bf2f(rv.y) : -1e30f;
    v[2] = (k0 + 2 < len) ? bf2f(rv.z) : -1e30f;
    v[3] = (k0 + 3 < len) ? bf2f(rv.w) : -1e30f;
#pragma unroll
    for (int j = 0; j < 4; ++j) mx = fmaxf(mx, v[j]);
#pragma unroll
    for (int off = 32; off; off >>= 1) mx = fmaxf(mx, __shfl_xor(mx, off));
    __shared__ float redm[4], reds[4];
    if ((tid & 63) == 0) redm[tid >> 6] = mx;
    __syncthreads();
    mx = fmaxf(fmaxf(redm[0], redm[1]), fmaxf(redm[2], redm[3]));
    float pv[4]; float sum = 0.f;
#pragma unroll
    for (int j = 0; j < 4; ++j) {
        pv[j] = (k0 + j < len) ? __expf(v[j] - mx) : 0.f;
        sum += pv[j];
    }
#pragma unroll
    for (int off = 32; off; off >>= 1) sum += __shfl_xor(sum, off);
    if ((tid & 63) == 0) reds[tid >> 6] = sum;
    __syncthreads();
    sum = reds[0] + reds[1] + reds[2] + reds[3];
    const float coef = wlr[h] / ((float)len * sum);
    const int Z = ((q >> 7) + 1) << 7;
    if (k0 < Z) {
        ushort4 wv4;
        wv4.x = f2bf(pv[0] * coef); wv4.y = f2bf(pv[1] * coef);
        wv4.z = f2bf(pv[2] * coef); wv4.w = f2bf(pv[3] * coef);
        *(ushort4*)&row[k0] = wv4;
    }
}

// y[b][q][h*D + d] = P[bh] . Vt[bh]^T  (K-loop causally truncated), bf16 out
__global__ __launch_bounds__(256) void k_pv(const ushort* __restrict__ P,
                                            const ushort* __restrict__ Vt,
                                            ushort* __restrict__ Y) {
    __shared__ __align__(16) ushort As[128 * 32], Bs[128 * 32];
    const int qt = blockIdx.x, dt = blockIdx.y, bh = blockIdx.z;
    ACC_INIT(acc);
    const ushort* A  = P + (size_t)bh * (S_ * S_) + (size_t)(qt * 128) * S_;
    const ushort* Bp = Vt + (size_t)bh * (D_ * S_) + (size_t)(dt * 128) * S_;
    gemm_nt_core(A, Bp, S_, S_, (qt + 1) * 4, As, Bs, acc);
    const int b = bh >> 3, h = bh & 7;
    ushort* C = Y + (size_t)b * (S_ * 8192) + (size_t)(qt * 128) * 8192 + h * D_ + dt * 128;
    const int w = threadIdx.x >> 6, l = threadIdx.x & 63;
    const int r0 = (w >> 1) * 64 + (l >> 4) * 4;
    const int c0 = (w & 1) * 64 + (l & 15);
#pragma unroll
    for (int m = 0; m < 4; ++m)
#pragma unroll
        for (int n = 0; n < 4; ++n)
#pragma unroll
            for (int j = 0; j < 4; ++j)
                C[(size_t)(r0 + m * 16 + j) * 8192 + c0 + n * 16] = f2bf(acc[m][n][j]);
}

// out[b] += y[b] . Wot^T  (split-K=2, atomicAdd) + exact fp32 b-term on kh==0
__global__ __launch_bounds__(256) void k_og(const ushort* __restrict__ Y,
                                            const ushort* __restrict__ Wot,
                                            const float* __restrict__ e,
                                            const float* __restrict__ wsE,
                                            float* __restrict__ out) {
    __shared__ __align__(16) ushort As[128 * 32], Bs[128 * 32];
    const int nt = blockIdx.x, mt = blockIdx.y;
    const int b = blockIdx.z >> 1, kh = blockIdx.z & 1;
    ACC_INIT(acc);
    const ushort* A  = Y + (size_t)b * (S_ * 8192) + (size_t)(mt * 128) * 8192 + kh * 4096;
    const ushort* Bp = Wot + (size_t)(nt * 128) * 8192 + kh * 4096;
    gemm_nt_core(A, Bp, 8192, 8192, 128, As, Bs, acc);
    const float invV = 1.f / (float)V_;
    const int w = threadIdx.x >> 6, l = threadIdx.x & 63;
    const int r0 = (w >> 1) * 64 + (l >> 4) * 4;
    const int c0 = (w & 1) * 64 + (l & 15);
#pragma unroll
    for (int m = 0; m < 4; ++m)
#pragma unroll
        for (int n = 0; n < 4; ++n)
#pragma unroll
            for (int j = 0; j < 4; ++j) {
                const int s    = mt * 128 + r0 + m * 16 + j;
                const int dcol = nt * 128 + c0 + n * 16;
                float add = acc[m][n][j];
                if (kh == 0) {
                    const float wn = 1.f / (float)(s + 1);
                    add += (e[(size_t)s * D_ + dcol] +
                            e[(size_t)(S_ * D_) + (size_t)s * D_ + dcol] -
                            2.f * wsE[dcol] * invV) * wn;
                }
                atomicAdd(&out[(size_t)(b * S_ + s) * D_ + dcol], add);
            }
}

// preps: bf16 casts / folds / transposes
__global__ __launch_bounds__(256) void k_prep_qk(const float* __restrict__ p,
                                                 const float* __restrict__ wq,
                                                 const float* __restrict__ wk,
                                                 ushort* __restrict__ Q,
                                                 ushort* __restrict__ K) {
    const int s = blockIdx.x, b = blockIdx.y;
    const int d0 = threadIdx.x * 4;
    const float4 pq = *(const float4*)&p[((size_t)b * SP1_ + s + 1) * D_ + d0];
    const float4 pk = *(const float4*)&p[((size_t)b * SP1_ + s) * D_ + d0];
    *(ushort4*)&Q[((size_t)b * S_ + s) * D_ + d0] =
        make_ushort4(f2bf(pq.x), f2bf(pq.y), f2bf(pq.z), f2bf(pq.w));
#pragma unroll
    for (int h = 0; h < H_; ++h) {
        const float4 a = *(const float4*)&wq[h * D_ + d0];
        const float4 c = *(const float4*)&wk[h * D_ + d0];
        *(ushort4*)&K[((size_t)(b * H_ + h) * S_ + s) * D_ + d0] =
            make_ushort4(f2bf(pk.x * a.x * c.x), f2bf(pk.y * a.y * c.y),
                         f2bf(pk.z * a.z * c.z), f2bf(pk.w * a.w * c.w));
    }
}

__global__ __launch_bounds__(256) void k_prep_v(const float* __restrict__ e,
                                                const float* __restrict__ wv,
                                                const float* __restrict__ wsE,
                                                ushort* __restrict__ Vt) {
    __shared__ float T[64][65];
    const int st = blockIdx.x, dt = blockIdx.y, b = blockIdx.z;
    const int tid = threadIdx.x;
    const int r = tid >> 2, cc = (tid & 3) * 16;
    const float invV = 1.f / (float)V_;
#pragma unroll
    for (int i = 0; i < 4; ++i) {
        const int c = cc + i * 4;
        float4 ev = *(const float4*)&e[((size_t)b * S_ + st * 64 + r) * D_ + dt * 64 + c];
        float4 Ev = *(const float4*)&wsE[dt * 64 + c];
        T[r][c + 0] = ev.x - Ev.x * invV;
        T[r][c + 1] = ev.y - Ev.y * invV;
        T[r][c + 2] = ev.z - Ev.z * invV;
        T[r][c + 3] = ev.w - Ev.w * invV;
    }
    __syncthreads();
    const int dd = tid >> 2, scc = (tid & 3) * 16;
#pragma unroll
    for (int h = 0; h < H_; ++h) {
        const float wvv = wv[h * D_ + dt * 64 + dd];
        ushort* dst = Vt + ((size_t)(b * H_ + h) * D_ + dt * 64 + dd) * S_ + st * 64 + scc;
#pragma unroll
        for (int i = 0; i < 4; ++i)
            *(ushort4*)&dst[i * 4] = make_ushort4(
                f2bf(T[scc + i * 4 + 0][dd] * wvv), f2bf(T[scc + i * 4 + 1][dd] * wvv),
                f2bf(T[scc + i * 4 + 2][dd] * wvv), f2bf(T[scc + i * 4 + 3][dd] * wvv));
    }
}

__global__ __launch_bounds__(256) void k_prep_wo(const float* __restrict__ wo,
                                                 ushort* __restrict__ Wot) {
    __shared__ float T[64][65];
    const int kt = blockIdx.x, nt = blockIdx.y;
    const int tid = threadIdx.x;
    const int r = tid >> 2, cc = (tid & 3) * 16;
#pragma unroll
    for (int i = 0; i < 4; ++i) {
        float4 v = *(const float4*)&wo[(size_t)(kt * 64 + r) * D_ + nt * 64 + cc + i * 4];
        T[r][cc + i * 4 + 0] = v.x; T[r][cc + i * 4 + 1] = v.y;
        T[r][cc + i * 4 + 2] = v.z; T[r][cc + i * 4 + 3] = v.w;
    }
    __syncthreads();
    const int nn = tid >> 2, sc2 = (tid & 3) * 16;
    ushort* dst = Wot + (size_t)(nt * 64 + nn) * 8192 + kt * 64 + sc2;
#pragma unroll
    for (int i = 0; i < 4; ++i)
        *(ushort4*)&dst[i * 4] = make_ushort4(
            f2bf(T[sc2 + i * 4 + 0][nn]), f2bf(T[sc2 + i * 4 + 1][nn]),
            f2bf(T[sc2 + i * 4 + 2][nn]), f2bf(T[sc2 + i * 4 + 3][nn]));
}

// ===========================================================================
// LEGACY PATH (needs 4 KB + 64 MB ws): round-1 fp32 kernels, proven correct
// ===========================================================================
__global__ __launch_bounds__(256) void k_attn_legacy(const float* __restrict__ e,
                                                     const float* __restrict__ p,
                                                     const float* __restrict__ wq,
                                                     const float* __restrict__ wk,
                                                     const float* __restrict__ wv,
                                                     const float* __restrict__ wlr,
                                                     const float* __restrict__ wsE,
                                                     float* __restrict__ ysc) {
    __shared__ __align__(16) float Kc[16][260];
    __shared__ __align__(16) float Stile[16][20];
    __shared__ __align__(16) float Wqk[D_];
    __shared__ float m_s[16], l_s[16], sc_s[16];

    const int tid = threadIdx.x;
    const int bid = blockIdx.x;
    const int bh  = bid & 15;
    const int qt  = 63 - (bid >> 4);
    const int b   = bh >> 3;
    const int h   = bh & 7;
    const int q0  = qt << 4;
    const int q   = tid >> 4;
    const int kk  = tid & 15;
    const int c0  = tid << 2;

    {
        float4 w1 = *(const float4*)&wq[h * D_ + tid * 4];
        float4 w2 = *(const float4*)&wk[h * D_ + tid * 4];
        float4 r; r.x = w1.x * w2.x; r.y = w1.y * w2.y; r.z = w1.z * w2.z; r.w = w1.w * w2.w;
        *(float4*)&Wqk[tid * 4] = r;
    }
    if (tid < 16) { m_s[tid] = -1e30f; l_s[tid] = 0.f; }
    __syncthreads();

    const float invV = 1.0f / (float)V_;
    float4 E4, Wv4;
    E4.x = wsE[c0 + 0] * invV; E4.y = wsE[c0 + 1] * invV;
    E4.z = wsE[c0 + 2] * invV; E4.w = wsE[c0 + 3] * invV;
    Wv4 = *(const float4*)&wv[h * D_ + c0];

    float acc[16][4];
#pragma unroll
    for (int i = 0; i < 16; ++i) { acc[i][0] = 0.f; acc[i][1] = 0.f; acc[i][2] = 0.f; acc[i][3] = 0.f; }

    const int    qg = q0 + q;
    const float* pq = p + ((size_t)b * SP1_ + (qg + 1)) * D_;

    for (int kt = 0; kt <= qt; ++kt) {
        const int k0 = kt << 4;
        float s = 0.f;
        for (int dc = 0; dc < 4; ++dc) {
            {
                const int row = tid >> 4, l16 = tid & 15;
                const float* pk = p + ((size_t)b * SP1_ + (k0 + row)) * D_ + dc * 256;
#pragma unroll
                for (int jj = 0; jj < 4; ++jj) {
                    const int col = l16 * 4 + jj * 64;
                    float4 a = *(const float4*)&pk[col];
                    float4 w = *(const float4*)&Wqk[dc * 256 + col];
                    float4 r; r.x = a.x * w.x; r.y = a.y * w.y; r.z = a.z * w.z; r.w = a.w * w.w;
                    *(float4*)&Kc[row][col] = r;
                }
            }
            __syncthreads();
            const float* pqc = pq + dc * 256;
#pragma unroll 8
            for (int j = 0; j < 64; ++j) {
                float4 a  = *(const float4*)&pqc[j * 4];
                float4 kc = *(const float4*)&Kc[kk][j * 4];
                s += a.x * kc.x + a.y * kc.y + a.z * kc.z + a.w * kc.w;
            }
            __syncthreads();
        }
        if (k0 + kk > qg) s = -1e30f;
        float rmax = s;
#pragma unroll
        for (int off = 8; off; off >>= 1) rmax = fmaxf(rmax, __shfl_xor(rmax, off, 16));
        const float m_old = m_s[q];
        const float m_new = fmaxf(m_old, rmax);
        const float pval  = __expf(s - m_new);
        float rsum = pval;
#pragma unroll
        for (int off = 8; off; off >>= 1) rsum += __shfl_xor(rsum, off, 16);
        if (kk == 0) {
            const float scale = __expf(m_old - m_new);
            sc_s[q] = scale;
            l_s[q]  = l_s[q] * scale + rsum;
            m_s[q]  = m_new;
        }
        Stile[q][kk] = pval;
        __syncthreads();
#pragma unroll
        for (int qq = 0; qq < 16; ++qq) {
            const float scq = sc_s[qq];
            acc[qq][0] *= scq; acc[qq][1] *= scq; acc[qq][2] *= scq; acc[qq][3] *= scq;
        }
#pragma unroll 1
        for (int kkc = 0; kkc < 4; ++kkc) {
            float4 Vr[4];
#pragma unroll
            for (int i = 0; i < 4; ++i) {
                const int k = k0 + kkc * 4 + i;
                float4 ev = *(const float4*)&e[((size_t)b * S_ + k) * D_ + c0];
                Vr[i].x = (ev.x - E4.x) * Wv4.x;
                Vr[i].y = (ev.y - E4.y) * Wv4.y;
                Vr[i].z = (ev.z - E4.z) * Wv4.z;
                Vr[i].w = (ev.w - E4.w) * Wv4.w;
            }
#pragma unroll
            for (int qq = 0; qq < 16; ++qq) {
                float4 pv = *(const float4*)&Stile[qq][kkc * 4];
                acc[qq][0] += pv.x * Vr[0].x + pv.y * Vr[1].x + pv.z * Vr[2].x + pv.w * Vr[3].x;
                acc[qq][1] += pv.x * Vr[0].y + pv.y * Vr[1].y + pv.z * Vr[2].y + pv.w * Vr[3].y;
                acc[qq][2] += pv.x * Vr[0].z + pv.y * Vr[1].z + pv.z * Vr[2].z + pv.w * Vr[3].z;
                acc[qq][3] += pv.x * Vr[0].w + pv.y * Vr[1].w + pv.z * Vr[2].w + pv.w * Vr[3].w;
            }
        }
        __syncthreads();
    }
    const float wlrh = wlr[h];
#pragma unroll
    for (int qq = 0; qq < 16; ++qq) {
        const int   qgq  = q0 + qq;
        const float coef = wlrh / ((float)(qgq + 1) * l_s[qq]);
        float4 r;
        r.x = acc[qq][0] * coef; r.y = acc[qq][1] * coef;
        r.z = acc[qq][2] * coef; r.w = acc[qq][3] * coef;
        *(float4*)&ysc[((size_t)bh * S_ + qgq) * D_ + c0] = r;
    }
}

__global__ __launch_bounds__(256) void k_out_legacy(const float* __restrict__ ysc,
                                                    const float* __restrict__ wo,
                                                    const float* __restrict__ e,
                                                    const float* __restrict__ wsE,
                                                    float* __restrict__ out) {
    __shared__ __align__(16) float Alds[16][132];
    __shared__ __align__(16) float Blds[16][132];
    const int tid = threadIdx.x;
    const int n0  = blockIdx.x * 128;
    const int m0  = blockIdx.y * 128;
    const int kh  = blockIdx.z;
    const int tx  = tid & 15, ty = tid >> 4;
    float acc[8][8];
#pragma unroll
    for (int i = 0; i < 8; ++i)
#pragma unroll
        for (int j = 0; j < 8; ++j) acc[i][j] = 0.f;
    const int    b     = m0 >> 10;
    const size_t Abase = (size_t)b * (H_ * (size_t)S_ * D_);
    const int    r0    = m0 & 1023;
    for (int kc = 0; kc < 256; ++kc) {
        const int k0 = kh * 4096 + kc * 16;
        {
            const int row = tid >> 1;
            const int cc  = (tid & 1) * 8;
            const float* src = ysc + Abase + (size_t)(r0 + row) * 8192 + k0 + cc;
            float4 a0 = *(const float4*)&src[0];
            float4 a1 = *(const float4*)&src[4];
            Alds[cc + 0][row] = a0.x; Alds[cc + 1][row] = a0.y;
            Alds[cc + 2][row] = a0.z; Alds[cc + 3][row] = a0.w;
            Alds[cc + 4][row] = a1.x; Alds[cc + 5][row] = a1.y;
            Alds[cc + 6][row] = a1.z; Alds[cc + 7][row] = a1.w;
        }
        {
            const int kr = tid >> 4;
            const int nn = (tid & 15) * 8;
            const float* src = wo + (size_t)(k0 + kr) * 1024 + n0 + nn;
            *(float4*)&Blds[kr][nn]     = *(const float4*)&src[0];
            *(float4*)&Blds[kr][nn + 4] = *(const float4*)&src[4];
        }
        __syncthreads();
#pragma unroll 4
        for (int k = 0; k < 16; ++k) {
            float4 a0 = *(const float4*)&Alds[k][ty * 4];
            float4 a1 = *(const float4*)&Alds[k][64 + ty * 4];
            float4 b0 = *(const float4*)&Blds[k][tx * 4];
            float4 b1 = *(const float4*)&Blds[k][64 + tx * 4];
            const float av[8] = {a0.x, a0.y, a0.z, a0.w, a1.x, a1.y, a1.z, a1.w};
            const float bv[8] = {b0.x, b0.y, b0.z, b0.w, b1.x, b1.y, b1.z, b1.w};
#pragma unroll
            for (int i = 0; i < 8; ++i)
#pragma unroll
                for (int j = 0; j < 8; ++j) acc[i][j] += av[i] * bv[j];
        }
        __syncthreads();
    }
    const float invV = 1.0f / (float)V_;
#pragma unroll
    for (int i = 0; i < 8; ++i) {
        const int lr = ((i >> 2) * 64) + ty * 4 + (i & 3);
        const int m  = m0 + lr;
        const int r  = m & 1023;
        const float wn = 1.0f / (float)(r + 1);
#pragma unroll
        for (int jg = 0; jg < 2; ++jg) {
            const int nc = n0 + jg * 64 + tx * 4;
            float add[4] = {0.f, 0.f, 0.f, 0.f};
            if (kh == 0) {
                float4 e0v = *(const float4*)&e[(size_t)r * 1024 + nc];
                float4 e1v = *(const float4*)&e[(size_t)(1024 * 1024) + (size_t)r * 1024 + nc];
                float4 Ev  = *(const float4*)&wsE[nc];
                add[0] = (e0v.x + e1v.x - 2.f * Ev.x * invV) * wn;
                add[1] = (e0v.y + e1v.y - 2.f * Ev.y * invV) * wn;
                add[2] = (e0v.z + e1v.z - 2.f * Ev.z * invV) * wn;
                add[3] = (e0v.w + e1v.w - 2.f * Ev.w * invV) * wn;
            }
#pragma unroll
            for (int jj = 0; jj < 4; ++jj) {
                const int j = (jg << 2) + jj;
                atomicAdd(&out[(size_t)m * 1024 + nc + jj], acc[i][j] + add[jj]);
            }
        }
    }
}

// ---------------------------------------------------------------------------
extern "C" void kernel_launch(void* const* d_in, const int* in_sizes, int n_in,
                              void* d_out, int out_size, void* d_ws, size_t ws_size,
                              hipStream_t stream) {
    const float* e   = (const float*)d_in[0];
    const float* p   = (const float*)d_in[1];
    const float* wte = (const float*)d_in[2];
    const float* wq  = (const float*)d_in[3];
    const float* wk  = (const float*)d_in[4];
    const float* wv  = (const float*)d_in[5];
    const float* wlr = (const float*)d_in[6];
    const float* wo  = (const float*)d_in[7];
    float* out = (float*)d_out;

    char*  ws  = (char*)d_ws;
    float* wsE = (float*)ws;                       // 4 KB, both paths

    const size_t MB = (size_t)1 << 20;
    const size_t FAST_NEED = 4096 + 100 * MB;      // SCP32 + Q4 + K/Y32 + Vt/Wot32

    hipMemsetAsync(wsE, 0, 1024 * sizeof(float), stream);
    hipMemsetAsync(out, 0, (size_t)B_ * S_ * D_ * sizeof(float), stream);
    k_wte_sum<<<256, 256, 0, stream>>>(wte, wsE);

    if (ws_size >= FAST_NEED) {
        // ---- fast path: bf16 MFMA pipeline, 100 MB ws with aliasing ----
        ushort* SCP = (ushort*)(ws + 4096);                  // 32 MB scores->P in place
        ushort* Q   = (ushort*)(ws + 4096 + 32 * MB);        // 4 MB
        ushort* KY  = (ushort*)(ws + 4096 + 36 * MB);        // 32 MB: K, then Y aliases
        ushort* VW  = (ushort*)(ws + 4096 + 68 * MB);        // 32 MB: Vt, then Wot aliases

        k_prep_qk<<<dim3(S_, B_), 256, 0, stream>>>(p, wq, wk, Q, KY);
        k_prep_v<<<dim3(16, 16, B_), 256, 0, stream>>>(e, wv, wsE, VW);
        k_qk<<<dim3(8, 8, 16), 256, 0, stream>>>(Q, KY, SCP);
        k_softmax<<<dim3(S_, 16), 256, 0, stream>>>(SCP, wlr);
        k_pv<<<dim3(8, 8, 16), 256, 0, stream>>>(SCP, VW, KY);          // Y over K
        k_prep_wo<<<dim3(128, 16), 256, 0, stream>>>(wo, VW);           // Wot over Vt
        k_og<<<dim3(8, 8, 4), 256, 0, stream>>>(KY, VW, e, wsE, out);
    } else {
        // ---- legacy path: proven round-1 fp32 kernels, 64 MB ws ----
        float* ysc = wsE + 1024;
        k_attn_legacy<<<1024, 256, 0, stream>>>(e, p, wq, wk, wv, wlr, wsE, ysc);
        k_out_legacy<<<dim3(8, 16, 2), 256, 0, stream>>>(ysc, wo, e, wsE, out);
    }
}

// Round 9
// 486.080 us; speedup vs baseline: 4.9569x; 1.0448x over previous
//
#include <hip/hip_runtime.h>

#define B_   2
#define S_   1024
#define D_   1024
#define H_   8
#define V_   32000
#define SP1_ 1025

typedef __attribute__((ext_vector_type(4))) float  f32x4;
typedef __attribute__((ext_vector_type(8))) __bf16 bf16x8;

__device__ inline ushort f2bf(float x) {            // RNE float -> bf16 bits
    union { float f; unsigned u; } v; v.f = x;
    unsigned r = v.u + 0x7FFFu + ((v.u >> 16) & 1u);
    return (ushort)(r >> 16);
}
__device__ inline float bf2f(ushort u) {
    union { unsigned u; float f; } v; v.u = (unsigned)u << 16; return v.f;
}

__device__ inline void gload_lds16(const void* g, void* l) {
    __builtin_amdgcn_global_load_lds((const __attribute__((address_space(1))) void*)g,
                                     (__attribute__((address_space(3))) void*)l,
                                     16, 0, 0);
}

// ---------------------------------------------------------------------------
// wte column sums (divide by V at use) — shared by both paths
// ---------------------------------------------------------------------------
__global__ __launch_bounds__(256) void k_wte_sum(const float* __restrict__ wte,
                                                 float* __restrict__ wsE) {
    const int tid = threadIdx.x;
    const int v0  = blockIdx.x * 125;
    float s0 = 0.f, s1 = 0.f, s2 = 0.f, s3 = 0.f;
    for (int i = 0; i < 125; ++i) {
        const float* row = wte + (size_t)(v0 + i) * D_;
        s0 += row[tid]; s1 += row[tid + 256]; s2 += row[tid + 512]; s3 += row[tid + 768];
    }
    atomicAdd(&wsE[tid], s0);       atomicAdd(&wsE[tid + 256], s1);
    atomicAdd(&wsE[tid + 512], s2); atomicAdd(&wsE[tid + 768], s3);
}

// ===========================================================================
// FAST PATH (needs 4 KB + 100 MB ws): bf16 MFMA pipeline
// ===========================================================================

// Shared NT-GEMM core v2: C(128x128) += A(128xK) * B(128xK)^T, bf16, BK=32,
// DOUBLE-BUFFERED stage-ahead (minimum 2-phase): STAGE(next) is issued before
// the ds_read+MFMA of the current tile; the single __syncthreads() (which
// drains vmcnt(0)) at iteration end covers both hazards. Hides HBM/L3 latency
// under MFMA even at 1 block/CU.
// 4 waves; wave (w>>1, w&1) owns a 64x64 quadrant (4x4 frags of 16x16x32).
// LDS: As/Bs each [2][128*32] ushort = 32 KB total.
__device__ __forceinline__ void gemm_nt_core(const ushort* __restrict__ A,
                                             const ushort* __restrict__ B,
                                             int lda, int ldb, int kSteps,
                                             ushort* As, ushort* Bs,
                                             f32x4 acc[4][4]) {
    const int tid = threadIdx.x;
    const int w   = tid >> 6;
    const int l   = tid & 63;
    const int sr  = l >> 2;          // staging row-sub 0..15
    const int sc  = (l & 3) * 8;     // staging col-octet
    const int fr  = l & 15;          // frag row/col
    const int fko = (l >> 4) * 8;    // frag k-octet
    const int ca  = w * 2, cb = w * 2 + 1;   // this wave's 16-row chunks

    const ushort* a0 = A + (size_t)sr * lda + sc;
    const ushort* b0 = B + (size_t)sr * ldb + sc;

#define STAGE_(kt_, buf_)                                                          \
    {                                                                              \
        const int k0_ = (kt_) * 32;                                                \
        gload_lds16(a0 + (size_t)(ca * 16) * lda + k0_, As + (buf_) * 4096 + ca * 512); \
        gload_lds16(b0 + (size_t)(ca * 16) * ldb + k0_, Bs + (buf_) * 4096 + ca * 512); \
        gload_lds16(a0 + (size_t)(cb * 16) * lda + k0_, As + (buf_) * 4096 + cb * 512); \
        gload_lds16(b0 + (size_t)(cb * 16) * ldb + k0_, Bs + (buf_) * 4096 + cb * 512); \
    }

    STAGE_(0, 0);
    __syncthreads();                          // vmcnt(0) drain: buf0 ready
    int cur = 0;
    for (int kt = 0; kt < kSteps; ++kt) {
        if (kt + 1 < kSteps) STAGE_(kt + 1, cur ^ 1);   // in flight during MFMA
        const ushort* Ar = As + cur * 4096;
        const ushort* Br = Bs + cur * 4096;
        bf16x8 av[4], bv[4];
#pragma unroll
        for (int m = 0; m < 4; ++m)
            av[m] = *(const bf16x8*)(Ar + ((w >> 1) * 64 + m * 16 + fr) * 32 + fko);
#pragma unroll
        for (int n = 0; n < 4; ++n)
            bv[n] = *(const bf16x8*)(Br + ((w & 1) * 64 + n * 16 + fr) * 32 + fko);
#pragma unroll
        for (int m = 0; m < 4; ++m)
#pragma unroll
            for (int n = 0; n < 4; ++n)
                acc[m][n] = __builtin_amdgcn_mfma_f32_16x16x32_bf16(av[m], bv[n], acc[m][n], 0, 0, 0);
        __syncthreads();   // drains vmcnt(0): next buf staged; cur reads done
        cur ^= 1;
    }
#undef STAGE_
}

#define ACC_INIT(acc)                                            \
    f32x4 acc[4][4];                                             \
    _Pragma("unroll") for (int m_ = 0; m_ < 4; ++m_)             \
        _Pragma("unroll") for (int n_ = 0; n_ < 4; ++n_)         \
            acc[m_][n_] = (f32x4){0.f, 0.f, 0.f, 0.f};

// scores[bh][q][k] = Q[b] . K[bh]^T  -> bf16 into SCP (triangular tiles)
__global__ __launch_bounds__(256) void k_qk(const ushort* __restrict__ Q,
                                            const ushort* __restrict__ K,
                                            ushort* __restrict__ SCP) {
    __shared__ __align__(16) ushort As[2 * 4096], Bs[2 * 4096];
    const int qt = blockIdx.x, kt = blockIdx.y, bh = blockIdx.z;
    if (kt > qt) return;
    ACC_INIT(acc);
    const ushort* A  = Q + (size_t)(bh >> 3) * (S_ * D_) + (size_t)(qt * 128) * D_;
    const ushort* Bp = K + (size_t)bh * (S_ * D_) + (size_t)(kt * 128) * D_;
    gemm_nt_core(A, Bp, D_, D_, 32, As, Bs, acc);
    ushort* C = SCP + (size_t)bh * (S_ * S_) + (size_t)(qt * 128) * S_ + kt * 128;
    const int w = threadIdx.x >> 6, l = threadIdx.x & 63;
    const int r0 = (w >> 1) * 64 + (l >> 4) * 4;
    const int c0 = (w & 1) * 64 + (l & 15);
#pragma unroll
    for (int m = 0; m < 4; ++m)
#pragma unroll
        for (int n = 0; n < 4; ++n)
#pragma unroll
            for (int j = 0; j < 4; ++j)
                C[(size_t)(r0 + m * 16 + j) * S_ + c0 + n * 16] = f2bf(acc[m][n][j]);
}

// in-place row softmax over k<=q; folds wlr[h]*wn[q]/l; zeros tail to the
// 128-multiple so PV can run dense tiles.
__global__ __launch_bounds__(256) void k_softmax(ushort* __restrict__ SCP,
                                                 const float* __restrict__ wlr) {
    const int q = blockIdx.x, bh = blockIdx.y, h = bh & 7;
    const int tid = threadIdx.x;
    ushort* row = SCP + (size_t)bh * (S_ * S_) + (size_t)q * S_;
    const int len = q + 1;
    const int k0  = tid * 4;
    const ushort4 rv = *(const ushort4*)&row[k0];
    float v[4]; float mx = -1e30f;
    v[0] = (k0 + 0 < len) ? bf2f(rv.x) : -1e30f;
    v[1] = (k0 + 1 < len) ? bf2f(rv.y) : -1e30f;
    v[2] = (k0 + 2 < len) ? bf2f(rv.z) : -1e30f;
    v[3] = (k0 + 3 < len) ? bf2f(rv.w) : -1e30f;
#pragma unroll
    for (int j = 0; j < 4; ++j) mx = fmaxf(mx, v[j]);
#pragma unroll
    for (int off = 32; off; off >>= 1) mx = fmaxf(mx, __shfl_xor(mx, off));
    __shared__ float redm[4], reds[4];
    if ((tid & 63) == 0) redm[tid >> 6] = mx;
    __syncthreads();
    mx = fmaxf(fmaxf(redm[0], redm[1]), fmaxf(redm[2], redm[3]));
    float pv[4]; float sum = 0.f;
#pragma unroll
    for (int j = 0; j < 4; ++j) {
        pv[j] = (k0 + j < len) ? __expf(v[j] - mx) : 0.f;
        sum += pv[j];
    }
#pragma unroll
    for (int off = 32; off; off >>= 1) sum += __shfl_xor(sum, off);
    if ((tid & 63) == 0) reds[tid >> 6] = sum;
    __syncthreads();
    sum = reds[0] + reds[1] + reds[2] + reds[3];
    const float coef = wlr[h] / ((float)len * sum);
    const int Z = ((q >> 7) + 1) << 7;
    if (k0 < Z) {
        ushort4 wv4;
        wv4.x = f2bf(pv[0] * coef); wv4.y = f2bf(pv[1] * coef);
        wv4.z = f2bf(pv[2] * coef); wv4.w = f2bf(pv[3] * coef);
        *(ushort4*)&row[k0] = wv4;
    }
}

// y[b][q][h*D + d] = P[bh] . Vt[bh]^T  (K-loop causally truncated), bf16 out
__global__ __launch_bounds__(256) void k_pv(const ushort* __restrict__ P,
                                            const ushort* __restrict__ Vt,
                                            ushort* __restrict__ Y) {
    __shared__ __align__(16) ushort As[2 * 4096], Bs[2 * 4096];
    const int qt = blockIdx.x, dt = blockIdx.y, bh = blockIdx.z;
    ACC_INIT(acc);
    const ushort* A  = P + (size_t)bh * (S_ * S_) + (size_t)(qt * 128) * S_;
    const ushort* Bp = Vt + (size_t)bh * (D_ * S_) + (size_t)(dt * 128) * S_;
    gemm_nt_core(A, Bp, S_, S_, (qt + 1) * 4, As, Bs, acc);
    const int b = bh >> 3, h = bh & 7;
    ushort* C = Y + (size_t)b * (S_ * 8192) + (size_t)(qt * 128) * 8192 + h * D_ + dt * 128;
    const int w = threadIdx.x >> 6, l = threadIdx.x & 63;
    const int r0 = (w >> 1) * 64 + (l >> 4) * 4;
    const int c0 = (w & 1) * 64 + (l & 15);
#pragma unroll
    for (int m = 0; m < 4; ++m)
#pragma unroll
        for (int n = 0; n < 4; ++n)
#pragma unroll
            for (int j = 0; j < 4; ++j)
                C[(size_t)(r0 + m * 16 + j) * 8192 + c0 + n * 16] = f2bf(acc[m][n][j]);
}

// out[b] += y[b] . Wot^T  (split-K=8, atomicAdd) + exact fp32 b-term on kh==0
__global__ __launch_bounds__(256) void k_og(const ushort* __restrict__ Y,
                                            const ushort* __restrict__ Wot,
                                            const float* __restrict__ e,
                                            const float* __restrict__ wsE,
                                            float* __restrict__ out) {
    __shared__ __align__(16) ushort As[2 * 4096], Bs[2 * 4096];
    const int nt = blockIdx.x, mt = blockIdx.y;
    const int b = blockIdx.z >> 3, kh = blockIdx.z & 7;    // K chunk: kh*1024
    ACC_INIT(acc);
    const ushort* A  = Y + (size_t)b * (S_ * 8192) + (size_t)(mt * 128) * 8192 + kh * 1024;
    const ushort* Bp = Wot + (size_t)(nt * 128) * 8192 + kh * 1024;
    gemm_nt_core(A, Bp, 8192, 8192, 32, As, Bs, acc);
    const float invV = 1.f / (float)V_;
    const int w = threadIdx.x >> 6, l = threadIdx.x & 63;
    const int r0 = (w >> 1) * 64 + (l >> 4) * 4;
    const int c0 = (w & 1) * 64 + (l & 15);
#pragma unroll
    for (int m = 0; m < 4; ++m)
#pragma unroll
        for (int n = 0; n < 4; ++n)
#pragma unroll
            for (int j = 0; j < 4; ++j) {
                const int s    = mt * 128 + r0 + m * 16 + j;
                const int dcol = nt * 128 + c0 + n * 16;
                float add = acc[m][n][j];
                if (kh == 0) {
                    const float wn = 1.f / (float)(s + 1);
                    add += (e[(size_t)s * D_ + dcol] +
                            e[(size_t)(S_ * D_) + (size_t)s * D_ + dcol] -
                            2.f * wsE[dcol] * invV) * wn;
                }
                atomicAdd(&out[(size_t)(b * S_ + s) * D_ + dcol], add);
            }
}

// preps: bf16 casts / folds / transposes
__global__ __launch_bounds__(256) void k_prep_qk(const float* __restrict__ p,
                                                 const float* __restrict__ wq,
                                                 const float* __restrict__ wk,
                                                 ushort* __restrict__ Q,
                                                 ushort* __restrict__ K) {
    const int s = blockIdx.x, b = blockIdx.y;
    const int d0 = threadIdx.x * 4;
    const float4 pq = *(const float4*)&p[((size_t)b * SP1_ + s + 1) * D_ + d0];
    const float4 pk = *(const float4*)&p[((size_t)b * SP1_ + s) * D_ + d0];
    *(ushort4*)&Q[((size_t)b * S_ + s) * D_ + d0] =
        make_ushort4(f2bf(pq.x), f2bf(pq.y), f2bf(pq.z), f2bf(pq.w));
#pragma unroll
    for (int h = 0; h < H_; ++h) {
        const float4 a = *(const float4*)&wq[h * D_ + d0];
        const float4 c = *(const float4*)&wk[h * D_ + d0];
        *(ushort4*)&K[((size_t)(b * H_ + h) * S_ + s) * D_ + d0] =
            make_ushort4(f2bf(pk.x * a.x * c.x), f2bf(pk.y * a.y * c.y),
                         f2bf(pk.z * a.z * c.z), f2bf(pk.w * a.w * c.w));
    }
}

__global__ __launch_bounds__(256) void k_prep_v(const float* __restrict__ e,
                                                const float* __restrict__ wv,
                                                const float* __restrict__ wsE,
                                                ushort* __restrict__ Vt) {
    __shared__ float T[64][65];
    const int st = blockIdx.x, dt = blockIdx.y, b = blockIdx.z;
    const int tid = threadIdx.x;
    const int r = tid >> 2, cc = (tid & 3) * 16;
    const float invV = 1.f / (float)V_;
#pragma unroll
    for (int i = 0; i < 4; ++i) {
        const int c = cc + i * 4;
        float4 ev = *(const float4*)&e[((size_t)b * S_ + st * 64 + r) * D_ + dt * 64 + c];
        float4 Ev = *(const float4*)&wsE[dt * 64 + c];
        T[r][c + 0] = ev.x - Ev.x * invV;
        T[r][c + 1] = ev.y - Ev.y * invV;
        T[r][c + 2] = ev.z - Ev.z * invV;
        T[r][c + 3] = ev.w - Ev.w * invV;
    }
    __syncthreads();
    const int dd = tid >> 2, scc = (tid & 3) * 16;
#pragma unroll
    for (int h = 0; h < H_; ++h) {
        const float wvv = wv[h * D_ + dt * 64 + dd];
        ushort* dst = Vt + ((size_t)(b * H_ + h) * D_ + dt * 64 + dd) * S_ + st * 64 + scc;
#pragma unroll
        for (int i = 0; i < 4; ++i)
            *(ushort4*)&dst[i * 4] = make_ushort4(
                f2bf(T[scc + i * 4 + 0][dd] * wvv), f2bf(T[scc + i * 4 + 1][dd] * wvv),
                f2bf(T[scc + i * 4 + 2][dd] * wvv), f2bf(T[scc + i * 4 + 3][dd] * wvv));
    }
}

__global__ __launch_bounds__(256) void k_prep_wo(const float* __restrict__ wo,
                                                 ushort* __restrict__ Wot) {
    __shared__ float T[64][65];
    const int kt = blockIdx.x, nt = blockIdx.y;
    const int tid = threadIdx.x;
    const int r = tid >> 2, cc = (tid & 3) * 16;
#pragma unroll
    for (int i = 0; i < 4; ++i) {
        float4 v = *(const float4*)&wo[(size_t)(kt * 64 + r) * D_ + nt * 64 + cc + i * 4];
        T[r][cc + i * 4 + 0] = v.x; T[r][cc + i * 4 + 1] = v.y;
        T[r][cc + i * 4 + 2] = v.z; T[r][cc + i * 4 + 3] = v.w;
    }
    __syncthreads();
    const int nn = tid >> 2, sc2 = (tid & 3) * 16;
    ushort* dst = Wot + (size_t)(nt * 64 + nn) * 8192 + kt * 64 + sc2;
#pragma unroll
    for (int i = 0; i < 4; ++i)
        *(ushort4*)&dst[i * 4] = make_ushort4(
            f2bf(T[sc2 + i * 4 + 0][nn]), f2bf(T[sc2 + i * 4 + 1][nn]),
            f2bf(T[sc2 + i * 4 + 2][nn]), f2bf(T[sc2 + i * 4 + 3][nn]));
}

// ===========================================================================
// LEGACY PATH (needs 4 KB + 64 MB ws): round-1 fp32 kernels, proven correct
// ===========================================================================
__global__ __launch_bounds__(256) void k_attn_legacy(const float* __restrict__ e,
                                                     const float* __restrict__ p,
                                                     const float* __restrict__ wq,
                                                     const float* __restrict__ wk,
                                                     const float* __restrict__ wv,
                                                     const float* __restrict__ wlr,
                                                     const float* __restrict__ wsE,
                                                     float* __restrict__ ysc) {
    __shared__ __align__(16) float Kc[16][260];
    __shared__ __align__(16) float Stile[16][20];
    __shared__ __align__(16) float Wqk[D_];
    __shared__ float m_s[16], l_s[16], sc_s[16];

    const int tid = threadIdx.x;
    const int bid = blockIdx.x;
    const int bh  = bid & 15;
    const int qt  = 63 - (bid >> 4);
    const int b   = bh >> 3;
    const int h   = bh & 7;
    const int q0  = qt << 4;
    const int q   = tid >> 4;
    const int kk  = tid & 15;
    const int c0  = tid << 2;

    {
        float4 w1 = *(const float4*)&wq[h * D_ + tid * 4];
        float4 w2 = *(const float4*)&wk[h * D_ + tid * 4];
        float4 r; r.x = w1.x * w2.x; r.y = w1.y * w2.y; r.z = w1.z * w2.z; r.w = w1.w * w2.w;
        *(float4*)&Wqk[tid * 4] = r;
    }
    if (tid < 16) { m_s[tid] = -1e30f; l_s[tid] = 0.f; }
    __syncthreads();

    const float invV = 1.0f / (float)V_;
    float4 E4, Wv4;
    E4.x = wsE[c0 + 0] * invV; E4.y = wsE[c0 + 1] * invV;
    E4.z = wsE[c0 + 2] * invV; E4.w = wsE[c0 + 3] * invV;
    Wv4 = *(const float4*)&wv[h * D_ + c0];

    float acc[16][4];
#pragma unroll
    for (int i = 0; i < 16; ++i) { acc[i][0] = 0.f; acc[i][1] = 0.f; acc[i][2] = 0.f; acc[i][3] = 0.f; }

    const int    qg = q0 + q;
    const float* pq = p + ((size_t)b * SP1_ + (qg + 1)) * D_;

    for (int kt = 0; kt <= qt; ++kt) {
        const int k0 = kt << 4;
        float s = 0.f;
        for (int dc = 0; dc < 4; ++dc) {
            {
                const int row = tid >> 4, l16 = tid & 15;
                const float* pk = p + ((size_t)b * SP1_ + (k0 + row)) * D_ + dc * 256;
#pragma unroll
                for (int jj = 0; jj < 4; ++jj) {
                    const int col = l16 * 4 + jj * 64;
                    float4 a = *(const float4*)&pk[col];
                    float4 w = *(const float4*)&Wqk[dc * 256 + col];
                    float4 r; r.x = a.x * w.x; r.y = a.y * w.y; r.z = a.z * w.z; r.w = a.w * w.w;
                    *(float4*)&Kc[row][col] = r;
                }
            }
            __syncthreads();
            const float* pqc = pq + dc * 256;
#pragma unroll 8
            for (int j = 0; j < 64; ++j) {
                float4 a  = *(const float4*)&pqc[j * 4];
                float4 kc = *(const float4*)&Kc[kk][j * 4];
                s += a.x * kc.x + a.y * kc.y + a.z * kc.z + a.w * kc.w;
            }
            __syncthreads();
        }
        if (k0 + kk > qg) s = -1e30f;
        float rmax = s;
#pragma unroll
        for (int off = 8; off; off >>= 1) rmax = fmaxf(rmax, __shfl_xor(rmax, off, 16));
        const float m_old = m_s[q];
        const float m_new = fmaxf(m_old, rmax);
        const float pval  = __expf(s - m_new);
        float rsum = pval;
#pragma unroll
        for (int off = 8; off; off >>= 1) rsum += __shfl_xor(rsum, off, 16);
        if (kk == 0) {
            const float scale = __expf(m_old - m_new);
            sc_s[q] = scale;
            l_s[q]  = l_s[q] * scale + rsum;
            m_s[q]  = m_new;
        }
        Stile[q][kk] = pval;
        __syncthreads();
#pragma unroll
        for (int qq = 0; qq < 16; ++qq) {
            const float scq = sc_s[qq];
            acc[qq][0] *= scq; acc[qq][1] *= scq; acc[qq][2] *= scq; acc[qq][3] *= scq;
        }
#pragma unroll 1
        for (int kkc = 0; kkc < 4; ++kkc) {
            float4 Vr[4];
#pragma unroll
            for (int i = 0; i < 4; ++i) {
                const int k = k0 + kkc * 4 + i;
                float4 ev = *(const float4*)&e[((size_t)b * S_ + k) * D_ + c0];
                Vr[i].x = (ev.x - E4.x) * Wv4.x;
                Vr[i].y = (ev.y - E4.y) * Wv4.y;
                Vr[i].z = (ev.z - E4.z) * Wv4.z;
                Vr[i].w = (ev.w - E4.w) * Wv4.w;
            }
#pragma unroll
            for (int qq = 0; qq < 16; ++qq) {
                float4 pv = *(const float4*)&Stile[qq][kkc * 4];
                acc[qq][0] += pv.x * Vr[0].x + pv.y * Vr[1].x + pv.z * Vr[2].x + pv.w * Vr[3].x;
                acc[qq][1] += pv.x * Vr[0].y + pv.y * Vr[1].y + pv.z * Vr[2].y + pv.w * Vr[3].y;
                acc[qq][2] += pv.x * Vr[0].z + pv.y * Vr[1].z + pv.z * Vr[2].z + pv.w * Vr[3].z;
                acc[qq][3] += pv.x * Vr[0].w + pv.y * Vr[1].w + pv.z * Vr[2].w + pv.w * Vr[3].w;
            }
        }
        __syncthreads();
    }
    const float wlrh = wlr[h];
#pragma unroll
    for (int qq = 0; qq < 16; ++qq) {
        const int   qgq  = q0 + qq;
        const float coef = wlrh / ((float)(qgq + 1) * l_s[qq]);
        float4 r;
        r.x = acc[qq][0] * coef; r.y = acc[qq][1] * coef;
        r.z = acc[qq][2] * coef; r.w = acc[qq][3] * coef;
        *(float4*)&ysc[((size_t)bh * S_ + qgq) * D_ + c0] = r;
    }
}

__global__ __launch_bounds__(256) void k_out_legacy(const float* __restrict__ ysc,
                                                    const float* __restrict__ wo,
                                                    const float* __restrict__ e,
                                                    const float* __restrict__ wsE,
                                                    float* __restrict__ out) {
    __shared__ __align__(16) float Alds[16][132];
    __shared__ __align__(16) float Blds[16][132];
    const int tid = threadIdx.x;
    const int n0  = blockIdx.x * 128;
    const int m0  = blockIdx.y * 128;
    const int kh  = blockIdx.z;
    const int tx  = tid & 15, ty = tid >> 4;
    float acc[8][8];
#pragma unroll
    for (int i = 0; i < 8; ++i)
#pragma unroll
        for (int j = 0; j < 8; ++j) acc[i][j] = 0.f;
    const int    b     = m0 >> 10;
    const size_t Abase = (size_t)b * (H_ * (size_t)S_ * D_);
    const int    r0    = m0 & 1023;
    for (int kc = 0; kc < 256; ++kc) {
        const int k0 = kh * 4096 + kc * 16;
        {
            const int row = tid >> 1;
            const int cc  = (tid & 1) * 8;
            const float* src = ysc + Abase + (size_t)(r0 + row) * 8192 + k0 + cc;
            float4 a0 = *(const float4*)&src[0];
            float4 a1 = *(const float4*)&src[4];
            Alds[cc + 0][row] = a0.x; Alds[cc + 1][row] = a0.y;
            Alds[cc + 2][row] = a0.z; Alds[cc + 3][row] = a0.w;
            Alds[cc + 4][row] = a1.x; Alds[cc + 5][row] = a1.y;
            Alds[cc + 6][row] = a1.z; Alds[cc + 7][row] = a1.w;
        }
        {
            const int kr = tid >> 4;
            const int nn = (tid & 15) * 8;
            const float* src = wo + (size_t)(k0 + kr) * 1024 + n0 + nn;
            *(float4*)&Blds[kr][nn]     = *(const float4*)&src[0];
            *(float4*)&Blds[kr][nn + 4] = *(const float4*)&src[4];
        }
        __syncthreads();
#pragma unroll 4
        for (int k = 0; k < 16; ++k) {
            float4 a0 = *(const float4*)&Alds[k][ty * 4];
            float4 a1 = *(const float4*)&Alds[k][64 + ty * 4];
            float4 b0 = *(const float4*)&Blds[k][tx * 4];
            float4 b1 = *(const float4*)&Blds[k][64 + tx * 4];
            const float av[8] = {a0.x, a0.y, a0.z, a0.w, a1.x, a1.y, a1.z, a1.w};
            const float bv[8] = {b0.x, b0.y, b0.z, b0.w, b1.x, b1.y, b1.z, b1.w};
#pragma unroll
            for (int i = 0; i < 8; ++i)
#pragma unroll
                for (int j = 0; j < 8; ++j) acc[i][j] += av[i] * bv[j];
        }
        __syncthreads();
    }
    const float invV = 1.0f / (float)V_;
#pragma unroll
    for (int i = 0; i < 8; ++i) {
        const int lr = ((i >> 2) * 64) + ty * 4 + (i & 3);
        const int m  = m0 + lr;
        const int r  = m & 1023;
        const float wn = 1.0f / (float)(r + 1);
#pragma unroll
        for (int jg = 0; jg < 2; ++jg) {
            const int nc = n0 + jg * 64 + tx * 4;
            float add[4] = {0.f, 0.f, 0.f, 0.f};
            if (kh == 0) {
                float4 e0v = *(const float4*)&e[(size_t)r * 1024 + nc];
                float4 e1v = *(const float4*)&e[(size_t)(1024 * 1024) + (size_t)r * 1024 + nc];
                float4 Ev  = *(const float4*)&wsE[nc];
                add[0] = (e0v.x + e1v.x - 2.f * Ev.x * invV) * wn;
                add[1] = (e0v.y + e1v.y - 2.f * Ev.y * invV) * wn;
                add[2] = (e0v.z + e1v.z - 2.f * Ev.z * invV) * wn;
                add[3] = (e0v.w + e1v.w - 2.f * Ev.w * invV) * wn;
            }
#pragma unroll
            for (int jj = 0; jj < 4; ++jj) {
                const int j = (jg << 2) + jj;
                atomicAdd(&out[(size_t)m * 1024 + nc + jj], acc[i][j] + add[jj]);
            }
        }
    }
}

// ---------------------------------------------------------------------------
extern "C" void kernel_launch(void* const* d_in, const int* in_sizes, int n_in,
                              void* d_out, int out_size, void* d_ws, size_t ws_size,
                              hipStream_t stream) {
    const float* e   = (const float*)d_in[0];
    const float* p   = (const float*)d_in[1];
    const float* wte = (const float*)d_in[2];
    const float* wq  = (const float*)d_in[3];
    const float* wk  = (const float*)d_in[4];
    const float* wv  = (const float*)d_in[5];
    const float* wlr = (const float*)d_in[6];
    const float* wo  = (const float*)d_in[7];
    float* out = (float*)d_out;

    char*  ws  = (char*)d_ws;
    float* wsE = (float*)ws;                       // 4 KB, both paths

    const size_t MB = (size_t)1 << 20;
    const size_t FAST_NEED = 4096 + 100 * MB;      // SCP32 + Q4 + K/Y32 + Vt/Wot32

    hipMemsetAsync(wsE, 0, 1024 * sizeof(float), stream);
    hipMemsetAsync(out, 0, (size_t)B_ * S_ * D_ * sizeof(float), stream);
    k_wte_sum<<<256, 256, 0, stream>>>(wte, wsE);

    if (ws_size >= FAST_NEED) {
        // ---- fast path: bf16 MFMA pipeline, 100 MB ws with aliasing ----
        ushort* SCP = (ushort*)(ws + 4096);                  // 32 MB scores->P in place
        ushort* Q   = (ushort*)(ws + 4096 + 32 * MB);        // 4 MB
        ushort* KY  = (ushort*)(ws + 4096 + 36 * MB);        // 32 MB: K, then Y aliases
        ushort* VW  = (ushort*)(ws + 4096 + 68 * MB);        // 32 MB: Vt, then Wot aliases

        k_prep_qk<<<dim3(S_, B_), 256, 0, stream>>>(p, wq, wk, Q, KY);
        k_prep_v<<<dim3(16, 16, B_), 256, 0, stream>>>(e, wv, wsE, VW);
        k_qk<<<dim3(8, 8, 16), 256, 0, stream>>>(Q, KY, SCP);
        k_softmax<<<dim3(S_, 16), 256, 0, stream>>>(SCP, wlr);
        k_pv<<<dim3(8, 8, 16), 256, 0, stream>>>(SCP, VW, KY);          // Y over K
        k_prep_wo<<<dim3(128, 16), 256, 0, stream>>>(wo, VW);           // Wot over Vt
        k_og<<<dim3(8, 8, 16), 256, 0, stream>>>(KY, VW, e, wsE, out);  // split-K=8
    } else {
        // ---- legacy path: proven round-1 fp32 kernels, 64 MB ws ----
        float* ysc = wsE + 1024;
        k_attn_legacy<<<1024, 256, 0, stream>>>(e, p, wq, wk, wv, wlr, wsE, ysc);
        k_out_legacy<<<dim3(8, 16, 2), 256, 0, stream>>>(ysc, wo, e, wsE, out);
    }
}

// Round 10
// 471.481 us; speedup vs baseline: 5.1104x; 1.0310x over previous
//
#include <hip/hip_runtime.h>

#define B_   2
#define S_   1024
#define D_   1024
#define H_   8
#define V_   32000
#define SP1_ 1025

typedef __attribute__((ext_vector_type(4))) float  f32x4;
typedef __attribute__((ext_vector_type(8))) __bf16 bf16x8;

__device__ inline ushort f2bf(float x) {            // RNE float -> bf16 bits
    union { float f; unsigned u; } v; v.f = x;
    unsigned r = v.u + 0x7FFFu + ((v.u >> 16) & 1u);
    return (ushort)(r >> 16);
}
__device__ inline float bf2f(ushort u) {
    union { unsigned u; float f; } v; v.u = (unsigned)u << 16; return v.f;
}

__device__ inline void gload_lds16(const void* g, void* l) {
    __builtin_amdgcn_global_load_lds((const __attribute__((address_space(1))) void*)g,
                                     (__attribute__((address_space(3))) void*)l,
                                     16, 0, 0);
}

// ---------------------------------------------------------------------------
// wte column sums (divide by V at use) — shared by both paths
// ---------------------------------------------------------------------------
__global__ __launch_bounds__(256) void k_wte_sum(const float* __restrict__ wte,
                                                 float* __restrict__ wsE) {
    const int tid = threadIdx.x;
    const int v0  = blockIdx.x * 125;
    float s0 = 0.f, s1 = 0.f, s2 = 0.f, s3 = 0.f;
    for (int i = 0; i < 125; ++i) {
        const float* row = wte + (size_t)(v0 + i) * D_;
        s0 += row[tid]; s1 += row[tid + 256]; s2 += row[tid + 512]; s3 += row[tid + 768];
    }
    atomicAdd(&wsE[tid], s0);       atomicAdd(&wsE[tid + 256], s1);
    atomicAdd(&wsE[tid + 512], s2); atomicAdd(&wsE[tid + 768], s3);
}

// ===========================================================================
// FAST PATH (needs 4 KB + 100 MB ws): bf16 MFMA pipeline
// ===========================================================================

// Shared NT-GEMM core v3: C(128x128) += A(128xK) * B(128xK)^T, bf16, BK=64,
// double-buffered stage-ahead + XOR bank-swizzle.
// LDS tile: [128 rows][64 cols bf16] = 128 B rows, 8 x 16B slots per row.
// Physical slot p at row r holds LOGICAL slot p^(r&7)  (involution):
//   - staging: linear LDS dest (global_load_lds requirement, m104); the
//     per-lane GLOBAL source is pre-swizzled (lane t, round i covers
//     row=i*32+(t>>3), phys slot t&7 -> logical slot (t&7)^(row&7)).
//   - frag read: slot xs = ((kk*4)|sk) ^ (fr&7) -> lanes 0..15 hit bank
//     quads 4*(r&7): 2 lanes/bank = conflict-free (m136), vs 8-way before.
// MFMA order identical to two BK=32 steps -> bit-identical results.
// 4 waves; wave (w>>1, w&1) owns a 64x64 quadrant (4x4 frags of 16x16x32).
// LDS: As/Bs each [2][128*64] ushort = 64 KB total (2 blocks/CU).
__device__ __forceinline__ void gemm_nt_core(const ushort* __restrict__ A,
                                             const ushort* __restrict__ B,
                                             int lda, int ldb, int kSteps,
                                             ushort* As, ushort* Bs,
                                             f32x4 acc[4][4]) {
    const int tid = threadIdx.x;
    const int w   = tid >> 6;
    const int l   = tid & 63;
    const int fr  = l & 15;          // frag row/col
    const int sk  = l >> 4;          // frag k-slot (0..3)

    // pre-swizzled staging source pointers (kt-invariant part)
    const ushort* sa[4]; const ushort* sb[4];
#pragma unroll
    for (int i = 0; i < 4; ++i) {
        const int row = i * 32 + (tid >> 3);
        const int ls  = (tid & 7) ^ (row & 7);     // logical slot for this lane
        sa[i] = A + (size_t)row * lda + ls * 8;
        sb[i] = B + (size_t)row * ldb + ls * 8;
    }

#define STAGE_(kt_, buf_)                                                        \
    {                                                                            \
        const int k0_ = (kt_) * 64;                                              \
        _Pragma("unroll")                                                        \
        for (int i_ = 0; i_ < 4; ++i_) {                                         \
            gload_lds16(sa[i_] + k0_, As + (buf_) * 8192 + i_ * 2048 + w * 512); \
            gload_lds16(sb[i_] + k0_, Bs + (buf_) * 8192 + i_ * 2048 + w * 512); \
        }                                                                        \
    }

    STAGE_(0, 0);
    __syncthreads();                          // vmcnt(0) drain: buf0 ready
    int cur = 0;
    for (int kt = 0; kt < kSteps; ++kt) {
        if (kt + 1 < kSteps) STAGE_(kt + 1, cur ^ 1);   // in flight during MFMA
        const ushort* Ar = As + cur * 8192;
        const ushort* Br = Bs + cur * 8192;
#pragma unroll
        for (int kk = 0; kk < 2; ++kk) {
            const int xs = ((kk << 2) | sk) ^ (fr & 7);   // swizzled 16B slot
            bf16x8 av[4], bv[4];
#pragma unroll
            for (int m = 0; m < 4; ++m)
                av[m] = *(const bf16x8*)(Ar + ((w >> 1) * 64 + m * 16 + fr) * 64 + xs * 8);
#pragma unroll
            for (int n = 0; n < 4; ++n)
                bv[n] = *(const bf16x8*)(Br + ((w & 1) * 64 + n * 16 + fr) * 64 + xs * 8);
#pragma unroll
            for (int m = 0; m < 4; ++m)
#pragma unroll
                for (int n = 0; n < 4; ++n)
                    acc[m][n] = __builtin_amdgcn_mfma_f32_16x16x32_bf16(av[m], bv[n], acc[m][n], 0, 0, 0);
        }
        __syncthreads();   // drains vmcnt(0): next buf staged; cur reads done
        cur ^= 1;
    }
#undef STAGE_
}

#define ACC_INIT(acc)                                            \
    f32x4 acc[4][4];                                             \
    _Pragma("unroll") for (int m_ = 0; m_ < 4; ++m_)             \
        _Pragma("unroll") for (int n_ = 0; n_ < 4; ++n_)         \
            acc[m_][n_] = (f32x4){0.f, 0.f, 0.f, 0.f};

// scores[bh][q][k] = Q[b] . K[bh]^T  -> bf16 into SCP (triangular tiles)
__global__ __launch_bounds__(256) void k_qk(const ushort* __restrict__ Q,
                                            const ushort* __restrict__ K,
                                            ushort* __restrict__ SCP) {
    __shared__ __align__(16) ushort As[2 * 8192], Bs[2 * 8192];
    const int qt = blockIdx.x, kt = blockIdx.y, bh = blockIdx.z;
    if (kt > qt) return;
    ACC_INIT(acc);
    const ushort* A  = Q + (size_t)(bh >> 3) * (S_ * D_) + (size_t)(qt * 128) * D_;
    const ushort* Bp = K + (size_t)bh * (S_ * D_) + (size_t)(kt * 128) * D_;
    gemm_nt_core(A, Bp, D_, D_, 16, As, Bs, acc);
    ushort* C = SCP + (size_t)bh * (S_ * S_) + (size_t)(qt * 128) * S_ + kt * 128;
    const int w = threadIdx.x >> 6, l = threadIdx.x & 63;
    const int r0 = (w >> 1) * 64 + (l >> 4) * 4;
    const int c0 = (w & 1) * 64 + (l & 15);
#pragma unroll
    for (int m = 0; m < 4; ++m)
#pragma unroll
        for (int n = 0; n < 4; ++n)
#pragma unroll
            for (int j = 0; j < 4; ++j)
                C[(size_t)(r0 + m * 16 + j) * S_ + c0 + n * 16] = f2bf(acc[m][n][j]);
}

// in-place row softmax over k<=q; folds wlr[h]*wn[q]/l; zeros tail to the
// 128-multiple so PV can run dense tiles.
__global__ __launch_bounds__(256) void k_softmax(ushort* __restrict__ SCP,
                                                 const float* __restrict__ wlr) {
    const int q = blockIdx.x, bh = blockIdx.y, h = bh & 7;
    const int tid = threadIdx.x;
    ushort* row = SCP + (size_t)bh * (S_ * S_) + (size_t)q * S_;
    const int len = q + 1;
    const int k0  = tid * 4;
    const ushort4 rv = *(const ushort4*)&row[k0];
    float v[4]; float mx = -1e30f;
    v[0] = (k0 + 0 < len) ? bf2f(rv.x) : -1e30f;
    v[1] = (k0 + 1 < len) ? bf2f(rv.y) : -1e30f;
    v[2] = (k0 + 2 < len) ? bf2f(rv.z) : -1e30f;
    v[3] = (k0 + 3 < len) ? bf2f(rv.w) : -1e30f;
#pragma unroll
    for (int j = 0; j < 4; ++j) mx = fmaxf(mx, v[j]);
#pragma unroll
    for (int off = 32; off; off >>= 1) mx = fmaxf(mx, __shfl_xor(mx, off));
    __shared__ float redm[4], reds[4];
    if ((tid & 63) == 0) redm[tid >> 6] = mx;
    __syncthreads();
    mx = fmaxf(fmaxf(redm[0], redm[1]), fmaxf(redm[2], redm[3]));
    float pv[4]; float sum = 0.f;
#pragma unroll
    for (int j = 0; j < 4; ++j) {
        pv[j] = (k0 + j < len) ? __expf(v[j] - mx) : 0.f;
        sum += pv[j];
    }
#pragma unroll
    for (int off = 32; off; off >>= 1) sum += __shfl_xor(sum, off);
    if ((tid & 63) == 0) reds[tid >> 6] = sum;
    __syncthreads();
    sum = reds[0] + reds[1] + reds[2] + reds[3];
    const float coef = wlr[h] / ((float)len * sum);
    const int Z = ((q >> 7) + 1) << 7;
    if (k0 < Z) {
        ushort4 wv4;
        wv4.x = f2bf(pv[0] * coef); wv4.y = f2bf(pv[1] * coef);
        wv4.z = f2bf(pv[2] * coef); wv4.w = f2bf(pv[3] * coef);
        *(ushort4*)&row[k0] = wv4;
    }
}

// y[b][q][h*D + d] = P[bh] . Vt[bh]^T  (K-loop causally truncated), bf16 out
__global__ __launch_bounds__(256) void k_pv(const ushort* __restrict__ P,
                                            const ushort* __restrict__ Vt,
                                            ushort* __restrict__ Y) {
    __shared__ __align__(16) ushort As[2 * 8192], Bs[2 * 8192];
    const int qt = blockIdx.x, dt = blockIdx.y, bh = blockIdx.z;
    ACC_INIT(acc);
    const ushort* A  = P + (size_t)bh * (S_ * S_) + (size_t)(qt * 128) * S_;
    const ushort* Bp = Vt + (size_t)bh * (D_ * S_) + (size_t)(dt * 128) * S_;
    gemm_nt_core(A, Bp, S_, S_, (qt + 1) * 2, As, Bs, acc);
    const int b = bh >> 3, h = bh & 7;
    ushort* C = Y + (size_t)b * (S_ * 8192) + (size_t)(qt * 128) * 8192 + h * D_ + dt * 128;
    const int w = threadIdx.x >> 6, l = threadIdx.x & 63;
    const int r0 = (w >> 1) * 64 + (l >> 4) * 4;
    const int c0 = (w & 1) * 64 + (l & 15);
#pragma unroll
    for (int m = 0; m < 4; ++m)
#pragma unroll
        for (int n = 0; n < 4; ++n)
#pragma unroll
            for (int j = 0; j < 4; ++j)
                C[(size_t)(r0 + m * 16 + j) * 8192 + c0 + n * 16] = f2bf(acc[m][n][j]);
}

// out[b] += y[b] . Wot^T  (split-K=8, atomicAdd) + exact fp32 b-term on kh==0
__global__ __launch_bounds__(256) void k_og(const ushort* __restrict__ Y,
                                            const ushort* __restrict__ Wot,
                                            const float* __restrict__ e,
                                            const float* __restrict__ wsE,
                                            float* __restrict__ out) {
    __shared__ __align__(16) ushort As[2 * 8192], Bs[2 * 8192];
    const int nt = blockIdx.x, mt = blockIdx.y;
    const int b = blockIdx.z >> 3, kh = blockIdx.z & 7;    // K chunk: kh*1024
    ACC_INIT(acc);
    const ushort* A  = Y + (size_t)b * (S_ * 8192) + (size_t)(mt * 128) * 8192 + kh * 1024;
    const ushort* Bp = Wot + (size_t)(nt * 128) * 8192 + kh * 1024;
    gemm_nt_core(A, Bp, 8192, 8192, 16, As, Bs, acc);
    const float invV = 1.f / (float)V_;
    const int w = threadIdx.x >> 6, l = threadIdx.x & 63;
    const int r0 = (w >> 1) * 64 + (l >> 4) * 4;
    const int c0 = (w & 1) * 64 + (l & 15);
#pragma unroll
    for (int m = 0; m < 4; ++m)
#pragma unroll
        for (int n = 0; n < 4; ++n)
#pragma unroll
            for (int j = 0; j < 4; ++j) {
                const int s    = mt * 128 + r0 + m * 16 + j;
                const int dcol = nt * 128 + c0 + n * 16;
                float add = acc[m][n][j];
                if (kh == 0) {
                    const float wn = 1.f / (float)(s + 1);
                    add += (e[(size_t)s * D_ + dcol] +
                            e[(size_t)(S_ * D_) + (size_t)s * D_ + dcol] -
                            2.f * wsE[dcol] * invV) * wn;
                }
                atomicAdd(&out[(size_t)(b * S_ + s) * D_ + dcol], add);
            }
}

// preps: bf16 casts / folds / transposes
__global__ __launch_bounds__(256) void k_prep_qk(const float* __restrict__ p,
                                                 const float* __restrict__ wq,
                                                 const float* __restrict__ wk,
                                                 ushort* __restrict__ Q,
                                                 ushort* __restrict__ K) {
    const int s = blockIdx.x, b = blockIdx.y;
    const int d0 = threadIdx.x * 4;
    const float4 pq = *(const float4*)&p[((size_t)b * SP1_ + s + 1) * D_ + d0];
    const float4 pk = *(const float4*)&p[((size_t)b * SP1_ + s) * D_ + d0];
    *(ushort4*)&Q[((size_t)b * S_ + s) * D_ + d0] =
        make_ushort4(f2bf(pq.x), f2bf(pq.y), f2bf(pq.z), f2bf(pq.w));
#pragma unroll
    for (int h = 0; h < H_; ++h) {
        const float4 a = *(const float4*)&wq[h * D_ + d0];
        const float4 c = *(const float4*)&wk[h * D_ + d0];
        *(ushort4*)&K[((size_t)(b * H_ + h) * S_ + s) * D_ + d0] =
            make_ushort4(f2bf(pk.x * a.x * c.x), f2bf(pk.y * a.y * c.y),
                         f2bf(pk.z * a.z * c.z), f2bf(pk.w * a.w * c.w));
    }
}

__global__ __launch_bounds__(256) void k_prep_v(const float* __restrict__ e,
                                                const float* __restrict__ wv,
                                                const float* __restrict__ wsE,
                                                ushort* __restrict__ Vt) {
    __shared__ float T[64][65];
    const int st = blockIdx.x, dt = blockIdx.y, b = blockIdx.z;
    const int tid = threadIdx.x;
    const int r = tid >> 2, cc = (tid & 3) * 16;
    const float invV = 1.f / (float)V_;
#pragma unroll
    for (int i = 0; i < 4; ++i) {
        const int c = cc + i * 4;
        float4 ev = *(const float4*)&e[((size_t)b * S_ + st * 64 + r) * D_ + dt * 64 + c];
        float4 Ev = *(const float4*)&wsE[dt * 64 + c];
        T[r][c + 0] = ev.x - Ev.x * invV;
        T[r][c + 1] = ev.y - Ev.y * invV;
        T[r][c + 2] = ev.z - Ev.z * invV;
        T[r][c + 3] = ev.w - Ev.w * invV;
    }
    __syncthreads();
    const int dd = tid >> 2, scc = (tid & 3) * 16;
#pragma unroll
    for (int h = 0; h < H_; ++h) {
        const float wvv = wv[h * D_ + dt * 64 + dd];
        ushort* dst = Vt + ((size_t)(b * H_ + h) * D_ + dt * 64 + dd) * S_ + st * 64 + scc;
#pragma unroll
        for (int i = 0; i < 4; ++i)
            *(ushort4*)&dst[i * 4] = make_ushort4(
                f2bf(T[scc + i * 4 + 0][dd] * wvv), f2bf(T[scc + i * 4 + 1][dd] * wvv),
                f2bf(T[scc + i * 4 + 2][dd] * wvv), f2bf(T[scc + i * 4 + 3][dd] * wvv));
    }
}

__global__ __launch_bounds__(256) void k_prep_wo(const float* __restrict__ wo,
                                                 ushort* __restrict__ Wot) {
    __shared__ float T[64][65];
    const int kt = blockIdx.x, nt = blockIdx.y;
    const int tid = threadIdx.x;
    const int r = tid >> 2, cc = (tid & 3) * 16;
#pragma unroll
    for (int i = 0; i < 4; ++i) {
        float4 v = *(const float4*)&wo[(size_t)(kt * 64 + r) * D_ + nt * 64 + cc + i * 4];
        T[r][cc + i * 4 + 0] = v.x; T[r][cc + i * 4 + 1] = v.y;
        T[r][cc + i * 4 + 2] = v.z; T[r][cc + i * 4 + 3] = v.w;
    }
    __syncthreads();
    const int nn = tid >> 2, sc2 = (tid & 3) * 16;
    ushort* dst = Wot + (size_t)(nt * 64 + nn) * 8192 + kt * 64 + sc2;
#pragma unroll
    for (int i = 0; i < 4; ++i)
        *(ushort4*)&dst[i * 4] = make_ushort4(
            f2bf(T[sc2 + i * 4 + 0][nn]), f2bf(T[sc2 + i * 4 + 1][nn]),
            f2bf(T[sc2 + i * 4 + 2][nn]), f2bf(T[sc2 + i * 4 + 3][nn]));
}

// ===========================================================================
// LEGACY PATH (needs 4 KB + 64 MB ws): round-1 fp32 kernels, proven correct
// ===========================================================================
__global__ __launch_bounds__(256) void k_attn_legacy(const float* __restrict__ e,
                                                     const float* __restrict__ p,
                                                     const float* __restrict__ wq,
                                                     const float* __restrict__ wk,
                                                     const float* __restrict__ wv,
                                                     const float* __restrict__ wlr,
                                                     const float* __restrict__ wsE,
                                                     float* __restrict__ ysc) {
    __shared__ __align__(16) float Kc[16][260];
    __shared__ __align__(16) float Stile[16][20];
    __shared__ __align__(16) float Wqk[D_];
    __shared__ float m_s[16], l_s[16], sc_s[16];

    const int tid = threadIdx.x;
    const int bid = blockIdx.x;
    const int bh  = bid & 15;
    const int qt  = 63 - (bid >> 4);
    const int b   = bh >> 3;
    const int h   = bh & 7;
    const int q0  = qt << 4;
    const int q   = tid >> 4;
    const int kk  = tid & 15;
    const int c0  = tid << 2;

    {
        float4 w1 = *(const float4*)&wq[h * D_ + tid * 4];
        float4 w2 = *(const float4*)&wk[h * D_ + tid * 4];
        float4 r; r.x = w1.x * w2.x; r.y = w1.y * w2.y; r.z = w1.z * w2.z; r.w = w1.w * w2.w;
        *(float4*)&Wqk[tid * 4] = r;
    }
    if (tid < 16) { m_s[tid] = -1e30f; l_s[tid] = 0.f; }
    __syncthreads();

    const float invV = 1.0f / (float)V_;
    float4 E4, Wv4;
    E4.x = wsE[c0 + 0] * invV; E4.y = wsE[c0 + 1] * invV;
    E4.z = wsE[c0 + 2] * invV; E4.w = wsE[c0 + 3] * invV;
    Wv4 = *(const float4*)&wv[h * D_ + c0];

    float acc[16][4];
#pragma unroll
    for (int i = 0; i < 16; ++i) { acc[i][0] = 0.f; acc[i][1] = 0.f; acc[i][2] = 0.f; acc[i][3] = 0.f; }

    const int    qg = q0 + q;
    const float* pq = p + ((size_t)b * SP1_ + (qg + 1)) * D_;

    for (int kt = 0; kt <= qt; ++kt) {
        const int k0 = kt << 4;
        float s = 0.f;
        for (int dc = 0; dc < 4; ++dc) {
            {
                const int row = tid >> 4, l16 = tid & 15;
                const float* pk = p + ((size_t)b * SP1_ + (k0 + row)) * D_ + dc * 256;
#pragma unroll
                for (int jj = 0; jj < 4; ++jj) {
                    const int col = l16 * 4 + jj * 64;
                    float4 a = *(const float4*)&pk[col];
                    float4 w = *(const float4*)&Wqk[dc * 256 + col];
                    float4 r; r.x = a.x * w.x; r.y = a.y * w.y; r.z = a.z * w.z; r.w = a.w * w.w;
                    *(float4*)&Kc[row][col] = r;
                }
            }
            __syncthreads();
            const float* pqc = pq + dc * 256;
#pragma unroll 8
            for (int j = 0; j < 64; ++j) {
                float4 a  = *(const float4*)&pqc[j * 4];
                float4 kc = *(const float4*)&Kc[kk][j * 4];
                s += a.x * kc.x + a.y * kc.y + a.z * kc.z + a.w * kc.w;
            }
            __syncthreads();
        }
        if (k0 + kk > qg) s = -1e30f;
        float rmax = s;
#pragma unroll
        for (int off = 8; off; off >>= 1) rmax = fmaxf(rmax, __shfl_xor(rmax, off, 16));
        const float m_old = m_s[q];
        const float m_new = fmaxf(m_old, rmax);
        const float pval  = __expf(s - m_new);
        float rsum = pval;
#pragma unroll
        for (int off = 8; off; off >>= 1) rsum += __shfl_xor(rsum, off, 16);
        if (kk == 0) {
            const float scale = __expf(m_old - m_new);
            sc_s[q] = scale;
            l_s[q]  = l_s[q] * scale + rsum;
            m_s[q]  = m_new;
        }
        Stile[q][kk] = pval;
        __syncthreads();
#pragma unroll
        for (int qq = 0; qq < 16; ++qq) {
            const float scq = sc_s[qq];
            acc[qq][0] *= scq; acc[qq][1] *= scq; acc[qq][2] *= scq; acc[qq][3] *= scq;
        }
#pragma unroll 1
        for (int kkc = 0; kkc < 4; ++kkc) {
            float4 Vr[4];
#pragma unroll
            for (int i = 0; i < 4; ++i) {
                const int k = k0 + kkc * 4 + i;
                float4 ev = *(const float4*)&e[((size_t)b * S_ + k) * D_ + c0];
                Vr[i].x = (ev.x - E4.x) * Wv4.x;
                Vr[i].y = (ev.y - E4.y) * Wv4.y;
                Vr[i].z = (ev.z - E4.z) * Wv4.z;
                Vr[i].w = (ev.w - E4.w) * Wv4.w;
            }
#pragma unroll
            for (int qq = 0; qq < 16; ++qq) {
                float4 pv = *(const float4*)&Stile[qq][kkc * 4];
                acc[qq][0] += pv.x * Vr[0].x + pv.y * Vr[1].x + pv.z * Vr[2].x + pv.w * Vr[3].x;
                acc[qq][1] += pv.x * Vr[0].y + pv.y * Vr[1].y + pv.z * Vr[2].y + pv.w * Vr[3].y;
                acc[qq][2] += pv.x * Vr[0].z + pv.y * Vr[1].z + pv.z * Vr[2].z + pv.w * Vr[3].z;
                acc[qq][3] += pv.x * Vr[0].w + pv.y * Vr[1].w + pv.z * Vr[2].w + pv.w * Vr[3].w;
            }
        }
        __syncthreads();
    }
    const float wlrh = wlr[h];
#pragma unroll
    for (int qq = 0; qq < 16; ++qq) {
        const int   qgq  = q0 + qq;
        const float coef = wlrh / ((float)(qgq + 1) * l_s[qq]);
        float4 r;
        r.x = acc[qq][0] * coef; r.y = acc[qq][1] * coef;
        r.z = acc[qq][2] * coef; r.w = acc[qq][3] * coef;
        *(float4*)&ysc[((size_t)bh * S_ + qgq) * D_ + c0] = r;
    }
}

__global__ __launch_bounds__(256) void k_out_legacy(const float* __restrict__ ysc,
                                                    const float* __restrict__ wo,
                                                    const float* __restrict__ e,
                                                    const float* __restrict__ wsE,
                                                    float* __restrict__ out) {
    __shared__ __align__(16) float Alds[16][132];
    __shared__ __align__(16) float Blds[16][132];
    const int tid = threadIdx.x;
    const int n0  = blockIdx.x * 128;
    const int m0  = blockIdx.y * 128;
    const int kh  = blockIdx.z;
    const int tx  = tid & 15, ty = tid >> 4;
    float acc[8][8];
#pragma unroll
    for (int i = 0; i < 8; ++i)
#pragma unroll
        for (int j = 0; j < 8; ++j) acc[i][j] = 0.f;
    const int    b     = m0 >> 10;
    const size_t Abase = (size_t)b * (H_ * (size_t)S_ * D_);
    const int    r0    = m0 & 1023;
    for (int kc = 0; kc < 256; ++kc) {
        const int k0 = kh * 4096 + kc * 16;
        {
            const int row = tid >> 1;
            const int cc  = (tid & 1) * 8;
            const float* src = ysc + Abase + (size_t)(r0 + row) * 8192 + k0 + cc;
            float4 a0 = *(const float4*)&src[0];
            float4 a1 = *(const float4*)&src[4];
            Alds[cc + 0][row] = a0.x; Alds[cc + 1][row] = a0.y;
            Alds[cc + 2][row] = a0.z; Alds[cc + 3][row] = a0.w;
            Alds[cc + 4][row] = a1.x; Alds[cc + 5][row] = a1.y;
            Alds[cc + 6][row] = a1.z; Alds[cc + 7][row] = a1.w;
        }
        {
            const int kr = tid >> 4;
            const int nn = (tid & 15) * 8;
            const float* src = wo + (size_t)(k0 + kr) * 1024 + n0 + nn;
            *(float4*)&Blds[kr][nn]     = *(const float4*)&src[0];
            *(float4*)&Blds[kr][nn + 4] = *(const float4*)&src[4];
        }
        __syncthreads();
#pragma unroll 4
        for (int k = 0; k < 16; ++k) {
            float4 a0 = *(const float4*)&Alds[k][ty * 4];
            float4 a1 = *(const float4*)&Alds[k][64 + ty * 4];
            float4 b0 = *(const float4*)&Blds[k][tx * 4];
            float4 b1 = *(const float4*)&Blds[k][64 + tx * 4];
            const float av[8] = {a0.x, a0.y, a0.z, a0.w, a1.x, a1.y, a1.z, a1.w};
            const float bv[8] = {b0.x, b0.y, b0.z, b0.w, b1.x, b1.y, b1.z, b1.w};
#pragma unroll
            for (int i = 0; i < 8; ++i)
#pragma unroll
                for (int j = 0; j < 8; ++j) acc[i][j] += av[i] * bv[j];
        }
        __syncthreads();
    }
    const float invV = 1.0f / (float)V_;
#pragma unroll
    for (int i = 0; i < 8; ++i) {
        const int lr = ((i >> 2) * 64) + ty * 4 + (i & 3);
        const int m  = m0 + lr;
        const int r  = m & 1023;
        const float wn = 1.0f / (float)(r + 1);
#pragma unroll
        for (int jg = 0; jg < 2; ++jg) {
            const int nc = n0 + jg * 64 + tx * 4;
            float add[4] = {0.f, 0.f, 0.f, 0.f};
            if (kh == 0) {
                float4 e0v = *(const float4*)&e[(size_t)r * 1024 + nc];
                float4 e1v = *(const float4*)&e[(size_t)(1024 * 1024) + (size_t)r * 1024 + nc];
                float4 Ev  = *(const float4*)&wsE[nc];
                add[0] = (e0v.x + e1v.x - 2.f * Ev.x * invV) * wn;
                add[1] = (e0v.y + e1v.y - 2.f * Ev.y * invV) * wn;
                add[2] = (e0v.z + e1v.z - 2.f * Ev.z * invV) * wn;
                add[3] = (e0v.w + e1v.w - 2.f * Ev.w * invV) * wn;
            }
#pragma unroll
            for (int jj = 0; jj < 4; ++jj) {
                const int j = (jg << 2) + jj;
                atomicAdd(&out[(size_t)m * 1024 + nc + jj], acc[i][j] + add[jj]);
            }
        }
    }
}

// ---------------------------------------------------------------------------
extern "C" void kernel_launch(void* const* d_in, const int* in_sizes, int n_in,
                              void* d_out, int out_size, void* d_ws, size_t ws_size,
                              hipStream_t stream) {
    const float* e   = (const float*)d_in[0];
    const float* p   = (const float*)d_in[1];
    const float* wte = (const float*)d_in[2];
    const float* wq  = (const float*)d_in[3];
    const float* wk  = (const float*)d_in[4];
    const float* wv  = (const float*)d_in[5];
    const float* wlr = (const float*)d_in[6];
    const float* wo  = (const float*)d_in[7];
    float* out = (float*)d_out;

    char*  ws  = (char*)d_ws;
    float* wsE = (float*)ws;                       // 4 KB, both paths

    const size_t MB = (size_t)1 << 20;
    const size_t FAST_NEED = 4096 + 100 * MB;      // SCP32 + Q4 + K/Y32 + Vt/Wot32

    hipMemsetAsync(wsE, 0, 1024 * sizeof(float), stream);
    hipMemsetAsync(out, 0, (size_t)B_ * S_ * D_ * sizeof(float), stream);
    k_wte_sum<<<256, 256, 0, stream>>>(wte, wsE);

    if (ws_size >= FAST_NEED) {
        // ---- fast path: bf16 MFMA pipeline, 100 MB ws with aliasing ----
        ushort* SCP = (ushort*)(ws + 4096);                  // 32 MB scores->P in place
        ushort* Q   = (ushort*)(ws + 4096 + 32 * MB);        // 4 MB
        ushort* KY  = (ushort*)(ws + 4096 + 36 * MB);        // 32 MB: K, then Y aliases
        ushort* VW  = (ushort*)(ws + 4096 + 68 * MB);        // 32 MB: Vt, then Wot aliases

        k_prep_qk<<<dim3(S_, B_), 256, 0, stream>>>(p, wq, wk, Q, KY);
        k_prep_v<<<dim3(16, 16, B_), 256, 0, stream>>>(e, wv, wsE, VW);
        k_qk<<<dim3(8, 8, 16), 256, 0, stream>>>(Q, KY, SCP);
        k_softmax<<<dim3(S_, 16), 256, 0, stream>>>(SCP, wlr);
        k_pv<<<dim3(8, 8, 16), 256, 0, stream>>>(SCP, VW, KY);          // Y over K
        k_prep_wo<<<dim3(128, 16), 256, 0, stream>>>(wo, VW);           // Wot over Vt
        k_og<<<dim3(8, 8, 16), 256, 0, stream>>>(KY, VW, e, wsE, out);  // split-K=8
    } else {
        // ---- legacy path: proven round-1 fp32 kernels, 64 MB ws ----
        float* ysc = wsE + 1024;
        k_attn_legacy<<<1024, 256, 0, stream>>>(e, p, wq, wk, wv, wlr, wsE, ysc);
        k_out_legacy<<<dim3(8, 16, 2), 256, 0, stream>>>(ysc, wo, e, wsE, out);
    }
}